// Round 5
// baseline (1624.906 us; speedup 1.0000x reference)
//
#include <hip/hip_runtime.h>
#include <math.h>

// Problem dims
#define B_ 4
#define L_ 512
#define MROWS 2048
#define D_MODEL 384
#define N_LAYER 4
#define D_INNER 768
#define N_STATE 16
#define DT_RANK 24
#define D_CONV 4
#define VOCAB 1544
#define FEAT 1536

__device__ __forceinline__ float softplus_f(float x) { return x > 20.f ? x : log1pf(expf(x)); }
__device__ __forceinline__ float silu_f(float x) { return x / (1.f + __expf(-x)); }

// DPP row-rotate add: x + (x rotated by N within each 16-lane row).
template <int CTRL>
__device__ __forceinline__ float dpp_radd(float x) {
    int r = __builtin_amdgcn_update_dpp(0, __float_as_int(x), CTRL, 0xf, 0xf, true);
    return x + __int_as_float(r);
}

__device__ __forceinline__ float4 ld4_guard(const float* __restrict__ p, int k, int ke) {
    if (k + 3 < ke) return *(const float4*)(p + k);
    float4 r = make_float4(0.f, 0.f, 0.f, 0.f);
    if (k + 0 < ke) r.x = p[k + 0];
    if (k + 1 < ke) r.y = p[k + 1];
    if (k + 2 < ke) r.z = p[k + 2];
    return r;
}

// ---------------------------------------------------------------------------
// GEMM: C[m,n] (+)= sum_k A[m,k]*W[n,k].  128x64 tile, 8x4 microtile.
// RMSN: A row-normalized on the fly (rms over K) and scaled by nw[k].
// GATED: A[m,k] *= silu(gate[m,k]). ATOMIC: split-K atomicAdd.
// EPI: 0 none, 1 +bias (z==0 only if ATOMIC).
// M, N must be multiples of 128/64 (true for all call sites).
// ---------------------------------------------------------------------------
#define BM 128
#define BN 64
#define BK 16

template <int EPI, bool GATED, bool ATOMIC, bool RMSN>
__global__ __launch_bounds__(256) void gemm_bt(
    const float* __restrict__ A, const float* __restrict__ W,
    const float* __restrict__ bias, const float* __restrict__ gate,
    const float* __restrict__ nw,
    float* __restrict__ C, int M, int N, int K, int lda, int ldg, int ldc, int KC)
{
    __shared__ float As[2][BK][BM + 4];   // stride 132: staging writes 2-way only
    __shared__ float Ws[2][BK][BN + 4];   // stride 68
    __shared__ float sscale[BM];

    const int t  = threadIdx.x;
    const int tx = t & 15;        // n: 4 cols each
    const int ty = t >> 4;        // m: 8 rows each
    const int m0 = blockIdx.y * BM;
    const int n0 = blockIdx.x * BN;
    const int ks = blockIdx.z * KC;
    const int ke = min(K, ks + KC);

    const int sr = t >> 2;            // 0..63
    const int sc = (t & 3) << 2;      // 0,4,8,12

    if (RMSN) {
        // per-block row scales (K fully covered: used only with z=1, K=384)
        const int row = t >> 1, half = t & 1;
        const float* xr = A + (size_t)(m0 + row) * lda + half * (K / 2);
        float s = 0.f;
        for (int i = 0; i < K / 2; i += 4) {
            float4 v = *(const float4*)(xr + i);
            s += v.x * v.x + v.y * v.y + v.z * v.z + v.w * v.w;
        }
        s += __shfl_xor(s, 1, 64);
        if (!half) sscale[row] = rsqrtf(s / (float)K + 1e-5f);
        __syncthreads();
    }

    float4 ra0, ra1, rw, rg0, rg1, rnw;

    auto prefetch = [&](int k0) {
        ra0 = ld4_guard(A + (size_t)(m0 + sr) * lda, k0 + sc, ke);
        ra1 = ld4_guard(A + (size_t)(m0 + sr + 64) * lda, k0 + sc, ke);
        if (GATED) {
            rg0 = ld4_guard(gate + (size_t)(m0 + sr) * ldg, k0 + sc, ke);
            rg1 = ld4_guard(gate + (size_t)(m0 + sr + 64) * ldg, k0 + sc, ke);
        }
        if (RMSN) rnw = ld4_guard(nw, k0 + sc, ke);
        rw = ld4_guard(W + (size_t)(n0 + sr) * (size_t)K, k0 + sc, ke);
    };

    auto stage = [&](int p) {
        float4 a0 = ra0, a1 = ra1;
        if (GATED) {
            a0.x *= silu_f(rg0.x); a0.y *= silu_f(rg0.y); a0.z *= silu_f(rg0.z); a0.w *= silu_f(rg0.w);
            a1.x *= silu_f(rg1.x); a1.y *= silu_f(rg1.y); a1.z *= silu_f(rg1.z); a1.w *= silu_f(rg1.w);
        }
        if (RMSN) {
            float s0 = sscale[sr], s1 = sscale[sr + 64];
            a0.x *= s0 * rnw.x; a0.y *= s0 * rnw.y; a0.z *= s0 * rnw.z; a0.w *= s0 * rnw.w;
            a1.x *= s1 * rnw.x; a1.y *= s1 * rnw.y; a1.z *= s1 * rnw.z; a1.w *= s1 * rnw.w;
        }
        As[p][sc + 0][sr] = a0.x; As[p][sc + 1][sr] = a0.y;
        As[p][sc + 2][sr] = a0.z; As[p][sc + 3][sr] = a0.w;
        As[p][sc + 0][sr + 64] = a1.x; As[p][sc + 1][sr + 64] = a1.y;
        As[p][sc + 2][sr + 64] = a1.z; As[p][sc + 3][sr + 64] = a1.w;
        Ws[p][sc + 0][sr] = rw.x; Ws[p][sc + 1][sr] = rw.y;
        Ws[p][sc + 2][sr] = rw.z; Ws[p][sc + 3][sr] = rw.w;
    };

    prefetch(ks);
    stage(0);
    __syncthreads();

    float acc[8][4] = {};
    int p = 0;

    for (int k0 = ks; k0 < ke; k0 += BK) {
        const bool more = (k0 + BK < ke);
        if (more) prefetch(k0 + BK);
#pragma unroll
        for (int kk = 0; kk < BK; ++kk) {
            float a[8], b[4];
#pragma unroll
            for (int i = 0; i < 8; ++i) a[i] = As[p][kk][ty * 8 + i];
#pragma unroll
            for (int j = 0; j < 4; ++j) b[j] = Ws[p][kk][tx * 4 + j];
#pragma unroll
            for (int i = 0; i < 8; ++i)
#pragma unroll
                for (int j = 0; j < 4; ++j) acc[i][j] = fmaf(a[i], b[j], acc[i][j]);
        }
        if (more) {
            stage(p ^ 1);
            __syncthreads();
            p ^= 1;
        }
    }

    const int on0 = n0 + tx * 4;
#pragma unroll
    for (int i = 0; i < 8; ++i) {
        const size_t om = m0 + ty * 8 + i;
        if (ATOMIC) {
#pragma unroll
            for (int j = 0; j < 4; ++j) {
                float v = acc[i][j];
                if (EPI == 1 && blockIdx.z == 0) v += bias[on0 + j];
                atomicAdd(&C[om * ldc + on0 + j], v);
            }
        } else {
            float4 v;
            v.x = acc[i][0]; v.y = acc[i][1]; v.z = acc[i][2]; v.w = acc[i][3];
            if (EPI == 1) { v.x += bias[on0]; v.y += bias[on0+1]; v.z += bias[on0+2]; v.w += bias[on0+3]; }
            *(float4*)(C + om * ldc + on0) = v;
        }
    }
}

// ---------------------------------------------------------------------------
// Depthwise causal conv (width 4) + bias + SiLU, float4 over channels.
// ---------------------------------------------------------------------------
__global__ __launch_bounds__(256) void conv_silu_k(
    const float* __restrict__ xz, const float* __restrict__ w,
    const float* __restrict__ cb, float* __restrict__ u)
{
    int idx = blockIdx.x * 256 + threadIdx.x;
    if (idx >= MROWS * (D_INNER / 4)) return;
    int dq = idx % (D_INNER / 4);
    int m  = idx / (D_INNER / 4);
    int d0 = dq * 4;
    int b = m / L_, l = m % L_;
    float4 wq[4];
#pragma unroll
    for (int j = 0; j < 4; ++j) wq[j] = *(const float4*)(w + (d0 + j) * D_CONV);
    float acc[4];
#pragma unroll
    for (int j = 0; j < 4; ++j) acc[j] = cb[d0 + j];
#pragma unroll
    for (int tt = 0; tt < 4; ++tt) {
        int ll = l - 3 + tt;
        if (ll >= 0) {
            float4 xv = *(const float4*)(xz + (size_t)(b * L_ + ll) * (2 * D_INNER) + d0);
            acc[0] = fmaf(xv.x, ((const float*)&wq[0])[tt], acc[0]);
            acc[1] = fmaf(xv.y, ((const float*)&wq[1])[tt], acc[1]);
            acc[2] = fmaf(xv.z, ((const float*)&wq[2])[tt], acc[2]);
            acc[3] = fmaf(xv.w, ((const float*)&wq[3])[tt], acc[3]);
        }
    }
    float4 o = make_float4(silu_f(acc[0]), silu_f(acc[1]), silu_f(acc[2]), silu_f(acc[3]));
    *(float4*)(u + (size_t)m * D_INNER + d0) = o;
}

// ---------------------------------------------------------------------------
// Fused x_proj + dt_proj: per 32-row tile,
//   phase 1: T[32][56] = u_tile @ x_proj_W.T (K=768); cols 24..55 -> bc[M][32],
//            cols 0..23 kept in LDS.
//   phase 2: delta[32][768] = softplus(T24 @ dt_proj_W.T + dt_b).
// grid = 64 blocks of 256 threads.
// ---------------------------------------------------------------------------
__global__ __launch_bounds__(256) void xd_k(
    const float* __restrict__ u, const float* __restrict__ xW,
    const float* __restrict__ dtW, const float* __restrict__ dtb,
    float* __restrict__ bc, float* __restrict__ delta)
{
    __shared__ float Au[2][BK][32 + 4];
    __shared__ float Wx[2][BK][64 + 4];
    __shared__ float Tsh[32][28];

    const int t  = threadIdx.x;
    const int tx = t & 15;        // n: 4 each
    const int ty = t >> 4;        // m: 2 each
    const int m0 = blockIdx.x * 32;
    const int sr = t >> 2;
    const int sc = (t & 3) << 2;

    float4 ra, rw;
    auto prefetch = [&](int k0) {
        if (t < 128) ra = *(const float4*)(u + (size_t)(m0 + sr) * D_INNER + k0 + sc);
        rw = (sr < 56) ? *(const float4*)(xW + (size_t)sr * D_INNER + k0 + sc)
                       : make_float4(0.f, 0.f, 0.f, 0.f);
    };
    auto stage = [&](int p) {
        if (t < 128) {
            Au[p][sc + 0][sr] = ra.x; Au[p][sc + 1][sr] = ra.y;
            Au[p][sc + 2][sr] = ra.z; Au[p][sc + 3][sr] = ra.w;
        }
        Wx[p][sc + 0][sr] = rw.x; Wx[p][sc + 1][sr] = rw.y;
        Wx[p][sc + 2][sr] = rw.z; Wx[p][sc + 3][sr] = rw.w;
    };

    prefetch(0);
    stage(0);
    __syncthreads();

    float acc[2][4] = {};
    int p = 0;
    for (int k0 = 0; k0 < D_INNER; k0 += BK) {
        const bool more = (k0 + BK < D_INNER);
        if (more) prefetch(k0 + BK);
#pragma unroll
        for (int kk = 0; kk < BK; ++kk) {
            float a0 = Au[p][kk][ty * 2 + 0];
            float a1 = Au[p][kk][ty * 2 + 1];
            float b[4];
#pragma unroll
            for (int j = 0; j < 4; ++j) b[j] = Wx[p][kk][tx * 4 + j];
#pragma unroll
            for (int j = 0; j < 4; ++j) {
                acc[0][j] = fmaf(a0, b[j], acc[0][j]);
                acc[1][j] = fmaf(a1, b[j], acc[1][j]);
            }
        }
        if (more) { stage(p ^ 1); __syncthreads(); p ^= 1; }
    }

#pragma unroll
    for (int i = 0; i < 2; ++i) {
        int om = ty * 2 + i;
#pragma unroll
        for (int j = 0; j < 4; ++j) {
            int col = tx * 4 + j;
            if (col < 24)       Tsh[om][col] = acc[i][j];
            else if (col < 56)  bc[(size_t)(m0 + om) * 32 + col - 24] = acc[i][j];
        }
    }
    __syncthreads();

    // phase 2: thread t covers n = t, t+256, t+512
    float4 wreg[3][6];
    float breg[3];
#pragma unroll
    for (int r = 0; r < 3; ++r) {
        const float* wr = dtW + (size_t)(t + 256 * r) * DT_RANK;
#pragma unroll
        for (int q = 0; q < 6; ++q) wreg[r][q] = *(const float4*)(wr + q * 4);
        breg[r] = dtb[t + 256 * r];
    }
    for (int m = 0; m < 32; ++m) {
        float4 tv[6];
#pragma unroll
        for (int q = 0; q < 6; ++q) tv[q] = *(const float4*)&Tsh[m][q * 4];
        float d0 = breg[0], d1 = breg[1], d2 = breg[2];
#pragma unroll
        for (int q = 0; q < 6; ++q) {
            d0 = fmaf(tv[q].x, wreg[0][q].x, d0); d0 = fmaf(tv[q].y, wreg[0][q].y, d0);
            d0 = fmaf(tv[q].z, wreg[0][q].z, d0); d0 = fmaf(tv[q].w, wreg[0][q].w, d0);
            d1 = fmaf(tv[q].x, wreg[1][q].x, d1); d1 = fmaf(tv[q].y, wreg[1][q].y, d1);
            d1 = fmaf(tv[q].z, wreg[1][q].z, d1); d1 = fmaf(tv[q].w, wreg[1][q].w, d1);
            d2 = fmaf(tv[q].x, wreg[2][q].x, d2); d2 = fmaf(tv[q].y, wreg[2][q].y, d2);
            d2 = fmaf(tv[q].z, wreg[2][q].z, d2); d2 = fmaf(tv[q].w, wreg[2][q].w, d2);
        }
        float* dr = delta + (size_t)(m0 + m) * D_INNER;
        dr[t]       = softplus_f(d0);
        dr[t + 256] = softplus_f(d1);
        dr[t + 512] = softplus_f(d2);
    }
}

// ---------------------------------------------------------------------------
// Selective scan, LDS-chunked (64 steps). Block = 16 d x 16 n.
// B/C read from compact bc[M][32] (B cols 0..15, C cols 16..31).
// ---------------------------------------------------------------------------
#define SCH 64
__global__ __launch_bounds__(256) void scan_k(
    const float* __restrict__ delta, const float* __restrict__ u,
    const float* __restrict__ bc, const float* __restrict__ A_log,
    const float* __restrict__ Dp, float* __restrict__ y)
{
    __shared__ float sd[SCH][16], su[SCH][16], sB[SCH][16], sC[SCH][16];
    const int t  = threadIdx.x;
    const int n  = t & 15;
    const int dl = t >> 4;
    const int b  = blockIdx.x / (D_INNER / 16);
    const int dg = blockIdx.x % (D_INNER / 16);
    const int d  = dg * 16 + dl;

    const float Av = -expf(A_log[d * N_STATE + n]);
    const float Dd = Dp[d];
    const int lr = t >> 2;
    const int lc = (t & 3) << 2;
    float h = 0.f;

    for (int c0 = 0; c0 < L_; c0 += SCH) {
        const size_t mrow = (size_t)b * L_ + c0 + lr;
        const float4 vd = *(const float4*)(delta + mrow * D_INNER + dg * 16 + lc);
        const float4 vu = *(const float4*)(u     + mrow * D_INNER + dg * 16 + lc);
        const float4 vB = *(const float4*)(bc    + mrow * 32 + lc);
        const float4 vC = *(const float4*)(bc    + mrow * 32 + 16 + lc);
        __syncthreads();
        *(float4*)&sd[lr][lc] = vd;
        *(float4*)&su[lr][lc] = vu;
        *(float4*)&sB[lr][lc] = vB;
        *(float4*)&sC[lr][lc] = vC;
        __syncthreads();
#pragma unroll 8
        for (int j = 0; j < SCH; ++j) {
            float dv = sd[j][dl];
            float uv = su[j][dl];
            float e  = __expf(dv * Av);
            float c  = dv * uv * sB[j][n];
            h = fmaf(e, h, c);
            float p = h * sC[j][n];
            p = dpp_radd<0x128>(p);
            p = dpp_radd<0x124>(p);
            p = dpp_radd<0x122>(p);
            p = dpp_radd<0x121>(p);
            if (n == 0) y[((size_t)b * L_ + c0 + j) * D_INNER + d] = fmaf(uv, Dd, p);
        }
    }
}

// ---------------------------------------------------------------------------
extern "C" void kernel_launch(void* const* d_in, const int* in_sizes, int n_in,
                              void* d_out, int out_size, void* d_ws, size_t ws_size,
                              hipStream_t stream)
{
    const float* input_ids = (const float*)d_in[0];
    const float* fc_W      = (const float*)d_in[1];
    const float* fc_b      = (const float*)d_in[2];
    const float* in_proj_W = (const float*)d_in[3];
    const float* conv_W    = (const float*)d_in[4];
    const float* conv_b    = (const float*)d_in[5];
    const float* x_proj_W  = (const float*)d_in[6];
    const float* dt_proj_W = (const float*)d_in[7];
    const float* dt_proj_b = (const float*)d_in[8];
    const float* A_log     = (const float*)d_in[9];
    const float* Dp        = (const float*)d_in[10];
    const float* out_proj_W= (const float*)d_in[11];
    const float* norm_W    = (const float*)d_in[12];
    const float* normf_W   = (const float*)d_in[13];
    const float* head_W    = (const float*)d_in[14];
    float* out = (float*)d_out;

    float* ws       = (float*)d_ws;
    float* x_ws     = ws;                                    // M*384
    float* xz_ws    = x_ws    + (size_t)MROWS * D_MODEL;     // M*1536
    float* u_ws     = xz_ws   + (size_t)MROWS * 2 * D_INNER; // M*768
    float* bc_ws    = u_ws    + (size_t)MROWS * D_INNER;     // M*32
    float* delta_ws = bc_ws   + (size_t)MROWS * 32;          // M*768
    float* y_ws     = delta_ws+ (size_t)MROWS * D_INNER;     // M*768

    const dim3 blk(256);

    // x = input_ids @ fc_W.T + fc_b   (split-K=3, atomic into zeroed x)
    hipMemsetAsync(x_ws, 0, (size_t)MROWS * D_MODEL * sizeof(float), stream);
    gemm_bt<1, false, true, false><<<dim3(D_MODEL / BN, MROWS / BM, 3), blk, 0, stream>>>(
        input_ids, fc_W, fc_b, nullptr, nullptr, x_ws,
        MROWS, D_MODEL, VOCAB, VOCAB, 0, D_MODEL, 528);

    for (int i = 0; i < N_LAYER; ++i) {
        // xz = rmsnorm(x, norm_W) @ in_proj_W.T  (rmsnorm fused into A-path)
        gemm_bt<0, false, false, true><<<dim3(2 * D_INNER / BN, MROWS / BM, 1), blk, 0, stream>>>(
            x_ws, in_proj_W + (size_t)i * 2 * D_INNER * D_MODEL, nullptr, nullptr,
            norm_W + i * D_MODEL, xz_ws,
            MROWS, 2 * D_INNER, D_MODEL, D_MODEL, 0, 2 * D_INNER, D_MODEL);

        // u = silu(conv(xz[:, :768]) + conv_b)
        conv_silu_k<<<(MROWS * (D_INNER / 4) + 255) / 256, blk, 0, stream>>>(
            xz_ws, conv_W + (size_t)i * D_INNER * D_CONV, conv_b + i * D_INNER, u_ws);

        // bc = u @ x_proj_W[24:].T ; delta = softplus(u @ x_proj_W[:24].T @ dtW.T + b)
        xd_k<<<MROWS / 32, blk, 0, stream>>>(
            u_ws, x_proj_W + (size_t)i * 56 * D_INNER,
            dt_proj_W + (size_t)i * D_INNER * DT_RANK, dt_proj_b + i * D_INNER,
            bc_ws, delta_ws);

        // selective scan
        scan_k<<<B_ * (D_INNER / 16), blk, 0, stream>>>(
            delta_ws, u_ws, bc_ws, A_log + (size_t)i * D_INNER * N_STATE,
            Dp + i * D_INNER, y_ws);

        // x += (y * silu(res)) @ out_proj_W.T  (gated A, split-K=3, atomic residual)
        gemm_bt<0, true, true, false><<<dim3(D_MODEL / BN, MROWS / BM, 3), blk, 0, stream>>>(
            y_ws, out_proj_W + (size_t)i * D_MODEL * D_INNER, nullptr, xz_ws + D_INNER,
            nullptr, x_ws, MROWS, D_MODEL, D_INNER, D_INNER, 2 * D_INNER, D_MODEL, 256);
    }

    // out = rmsnorm(x, normf_W) @ head_W.T  (rmsnorm fused)
    gemm_bt<0, false, false, true><<<dim3(FEAT / BN, MROWS / BM, 1), blk, 0, stream>>>(
        x_ws, head_W, nullptr, nullptr, normf_W, out,
        MROWS, FEAT, D_MODEL, D_MODEL, 0, FEAT, D_MODEL);
}

// Round 6
// 1164.879 us; speedup vs baseline: 1.3949x; 1.3949x over previous
//
#include <hip/hip_runtime.h>
#include <math.h>

// Problem dims
#define B_ 4
#define L_ 512
#define MROWS 2048
#define D_MODEL 384
#define N_LAYER 4
#define D_INNER 768
#define N_STATE 16
#define DT_RANK 24
#define D_CONV 4
#define VOCAB 1544
#define FEAT 1536
#define XPROJ_N 56

__device__ __forceinline__ float softplus_f(float x) { return x > 20.f ? x : log1pf(expf(x)); }
__device__ __forceinline__ float silu_f(float x) { return x / (1.f + __expf(-x)); }

// DPP row-rotate add: x + (x rotated by N within each 16-lane row).
template <int CTRL>
__device__ __forceinline__ float dpp_radd(float x) {
    int r = __builtin_amdgcn_update_dpp(0, __float_as_int(x), CTRL, 0xf, 0xf, true);
    return x + __int_as_float(r);
}

__device__ __forceinline__ float4 ld4_guard(const float* __restrict__ p, int k, int ke) {
    if (k + 3 < ke) return *(const float4*)(p + k);
    float4 r = make_float4(0.f, 0.f, 0.f, 0.f);
    if (k + 0 < ke) r.x = p[k + 0];
    if (k + 1 < ke) r.y = p[k + 1];
    if (k + 2 < ke) r.z = p[k + 2];
    return r;
}

// ---------------------------------------------------------------------------
// Tiled GEMM: C[m,n] (+)= sum_k A[m,k] * W[n,k]   (W row-major NxK, stride K)
// EPI: 0 none, 1 +bias (z==0 split only if ATOMIC), 2 softplus(x+bias)
// GATED: A[m,k] *= silu(gate[m*ldg+k]);  ATOMIC: atomicAdd into C (split-K)
// RMSN:  A rows scaled by rsqrt(mean_k A^2)+1e-5) * nw[k]  (K=384 sites only,
//        never combined with split-K).
// 64x64 tile, 4x4 microtile (VGPR ~48 -> high occupancy); LDS pad +4 so
// staging writes alias exactly 2-way (free, m136).  // 128-tile regressed: 288
// blocks couldn't fill 256 CUs (r5: occ 28%->7%).
// ---------------------------------------------------------------------------
#define BM 64
#define BN 64
#define BK 16

template <int EPI, bool GATED, bool ATOMIC, bool RMSN>
__global__ __launch_bounds__(256) void gemm_bt(
    const float* __restrict__ A, const float* __restrict__ W,
    const float* __restrict__ bias, const float* __restrict__ gate,
    const float* __restrict__ nw,
    float* __restrict__ C, int M, int N, int K, int lda, int ldg, int ldc, int KC)
{
    __shared__ float As[2][BK][BM + 4];   // stride 68: 2-way staging alias only
    __shared__ float Ws[2][BK][BN + 4];
    __shared__ float sscale[BM];

    const int t  = threadIdx.x;
    const int tx = t & 15;        // n-dim (4 cols each)
    const int ty = t >> 4;        // m-dim (4 rows each)
    const int m0 = blockIdx.y * BM;
    const int n0 = blockIdx.x * BN;
    const int ks = blockIdx.z * KC;
    const int ke = min(K, ks + KC);

    const int sr = t >> 2;            // 0..63 tile row
    const int sc = (t & 3) << 2;      // 0,4,8,12 k-offset
    const int gm = m0 + sr;
    const int gn = n0 + sr;

    if (RMSN) {
        // per-row scale; K is the full reduction dim here (no split-K). 4 thr/row.
        const int row = t >> 2, q = t & 3;
        const float* xr = A + (size_t)(m0 + row) * lda + q * (K >> 2);
        float s = 0.f;
        for (int i = 0; i < (K >> 2); i += 4) {
            float4 v = *(const float4*)(xr + i);
            s += v.x * v.x + v.y * v.y + v.z * v.z + v.w * v.w;
        }
        s += __shfl_xor(s, 1, 64);
        s += __shfl_xor(s, 2, 64);
        if (q == 0) sscale[row] = rsqrtf(s / (float)K + 1e-5f);
        __syncthreads();
    }

    float4 ra = make_float4(0.f, 0.f, 0.f, 0.f), rw = ra, rg = ra, rnw = ra;

    auto prefetch = [&](int k0) {
        ra = make_float4(0.f, 0.f, 0.f, 0.f);
        rw = ra;
        if (gm < M) {
            ra = ld4_guard(A + (size_t)gm * lda, k0 + sc, ke);
            if (GATED) rg = ld4_guard(gate + (size_t)gm * ldg, k0 + sc, ke);
        }
        if (RMSN) rnw = ld4_guard(nw, k0 + sc, ke);
        if (gn < N) rw = ld4_guard(W + (size_t)gn * (size_t)K, k0 + sc, ke);
    };

    auto stage = [&](int p) {
        float4 a = ra;
        if (GATED) {
            a.x *= silu_f(rg.x); a.y *= silu_f(rg.y);
            a.z *= silu_f(rg.z); a.w *= silu_f(rg.w);
        }
        if (RMSN) {
            float s0 = sscale[sr];
            a.x *= s0 * rnw.x; a.y *= s0 * rnw.y; a.z *= s0 * rnw.z; a.w *= s0 * rnw.w;
        }
        As[p][sc + 0][sr] = a.x; As[p][sc + 1][sr] = a.y;
        As[p][sc + 2][sr] = a.z; As[p][sc + 3][sr] = a.w;
        Ws[p][sc + 0][sr] = rw.x; Ws[p][sc + 1][sr] = rw.y;
        Ws[p][sc + 2][sr] = rw.z; Ws[p][sc + 3][sr] = rw.w;
    };

    prefetch(ks);
    stage(0);
    __syncthreads();

    float acc[4][4] = {};
    int p = 0;

    for (int k0 = ks; k0 < ke; k0 += BK) {
        const bool more = (k0 + BK < ke);
        if (more) prefetch(k0 + BK);          // global loads in flight during compute
#pragma unroll
        for (int kk = 0; kk < BK; ++kk) {
            float a[4], b[4];
#pragma unroll
            for (int i = 0; i < 4; ++i) a[i] = As[p][kk][ty * 4 + i];
#pragma unroll
            for (int j = 0; j < 4; ++j) b[j] = Ws[p][kk][tx * 4 + j];
#pragma unroll
            for (int i = 0; i < 4; ++i)
#pragma unroll
                for (int j = 0; j < 4; ++j) acc[i][j] = fmaf(a[i], b[j], acc[i][j]);
        }
        if (more) {
            stage(p ^ 1);                     // buf p^1 not read until after barrier
            __syncthreads();
            p ^= 1;
        }
    }

#pragma unroll
    for (int i = 0; i < 4; ++i) {
        int om = m0 + ty * 4 + i;
        if (om >= M) continue;
        if (ATOMIC) {
#pragma unroll
            for (int j = 0; j < 4; ++j) {
                int on = n0 + tx * 4 + j;
                if (on >= N) continue;
                float v = acc[i][j];
                if (EPI == 1 && blockIdx.z == 0) v += bias[on];
                atomicAdd(&C[(size_t)om * ldc + on], v);
            }
        } else {
            int on0 = n0 + tx * 4;
            float v[4];
#pragma unroll
            for (int j = 0; j < 4; ++j) {
                v[j] = acc[i][j];
                if (EPI == 1 || EPI == 2) v[j] += bias[on0 + j < N ? on0 + j : 0];
                if (EPI == 2) v[j] = softplus_f(v[j]);
            }
            if (on0 + 3 < N) {
                *(float4*)(C + (size_t)om * ldc + on0) = make_float4(v[0], v[1], v[2], v[3]);
            } else {
#pragma unroll
                for (int j = 0; j < 4; ++j)
                    if (on0 + j < N) C[(size_t)om * ldc + on0 + j] = v[j];
            }
        }
    }
}

// ---------------------------------------------------------------------------
// Depthwise causal conv (width 4) + bias + SiLU, float4 over channels.
// ---------------------------------------------------------------------------
__global__ __launch_bounds__(256) void conv_silu_k(
    const float* __restrict__ xz, const float* __restrict__ w,
    const float* __restrict__ cb, float* __restrict__ u)
{
    int idx = blockIdx.x * 256 + threadIdx.x;
    if (idx >= MROWS * (D_INNER / 4)) return;
    int dq = idx % (D_INNER / 4);
    int m  = idx / (D_INNER / 4);
    int d0 = dq * 4;
    int b = m / L_, l = m % L_;
    float4 wq[4];
#pragma unroll
    for (int j = 0; j < 4; ++j) wq[j] = *(const float4*)(w + (d0 + j) * D_CONV);
    float acc[4];
#pragma unroll
    for (int j = 0; j < 4; ++j) acc[j] = cb[d0 + j];
#pragma unroll
    for (int tt = 0; tt < 4; ++tt) {
        int ll = l - 3 + tt;
        if (ll >= 0) {
            float4 xv = *(const float4*)(xz + (size_t)(b * L_ + ll) * (2 * D_INNER) + d0);
            acc[0] = fmaf(xv.x, ((const float*)&wq[0])[tt], acc[0]);
            acc[1] = fmaf(xv.y, ((const float*)&wq[1])[tt], acc[1]);
            acc[2] = fmaf(xv.z, ((const float*)&wq[2])[tt], acc[2]);
            acc[3] = fmaf(xv.w, ((const float*)&wq[3])[tt], acc[3]);
        }
    }
    float4 o = make_float4(silu_f(acc[0]), silu_f(acc[1]), silu_f(acc[2]), silu_f(acc[3]));
    *(float4*)(u + (size_t)m * D_INNER + d0) = o;
}

// ---------------------------------------------------------------------------
// Selective scan, LDS-chunked (64 steps). Block = 16 d x 16 n.
// Reduction over the 16 states via DPP row rotations (VALU, no LDS pipe).
// ---------------------------------------------------------------------------
#define SCH 64
__global__ __launch_bounds__(256) void scan_k(
    const float* __restrict__ delta, const float* __restrict__ u,
    const float* __restrict__ xdbl, const float* __restrict__ A_log,
    const float* __restrict__ Dp, float* __restrict__ y)
{
    __shared__ float sd[SCH][16], su[SCH][16], sB[SCH][16], sC[SCH][16];
    const int t  = threadIdx.x;
    const int n  = t & 15;
    const int dl = t >> 4;
    const int b  = blockIdx.x / (D_INNER / 16);
    const int dg = blockIdx.x % (D_INNER / 16);
    const int d  = dg * 16 + dl;

    const float Av = -expf(A_log[d * N_STATE + n]);
    const float Dd = Dp[d];
    const int lr = t >> 2;
    const int lc = (t & 3) << 2;
    float h = 0.f;

    for (int c0 = 0; c0 < L_; c0 += SCH) {
        const size_t mrow = (size_t)b * L_ + c0 + lr;
        const float4 vd = *(const float4*)(delta + mrow * D_INNER + dg * 16 + lc);
        const float4 vu = *(const float4*)(u     + mrow * D_INNER + dg * 16 + lc);
        const float4 vB = *(const float4*)(xdbl  + mrow * XPROJ_N + DT_RANK + lc);
        const float4 vC = *(const float4*)(xdbl  + mrow * XPROJ_N + DT_RANK + N_STATE + lc);
        __syncthreads();
        *(float4*)&sd[lr][lc] = vd;
        *(float4*)&su[lr][lc] = vu;
        *(float4*)&sB[lr][lc] = vB;
        *(float4*)&sC[lr][lc] = vC;
        __syncthreads();
#pragma unroll 8
        for (int j = 0; j < SCH; ++j) {
            float dv = sd[j][dl];
            float uv = su[j][dl];
            float e  = __expf(dv * Av);
            float c  = dv * uv * sB[j][n];
            h = fmaf(e, h, c);
            float p = h * sC[j][n];
            p = dpp_radd<0x128>(p);
            p = dpp_radd<0x124>(p);
            p = dpp_radd<0x122>(p);
            p = dpp_radd<0x121>(p);
            if (n == 0) y[((size_t)b * L_ + c0 + j) * D_INNER + d] = fmaf(uv, Dd, p);
        }
    }
}

// ---------------------------------------------------------------------------
extern "C" void kernel_launch(void* const* d_in, const int* in_sizes, int n_in,
                              void* d_out, int out_size, void* d_ws, size_t ws_size,
                              hipStream_t stream)
{
    const float* input_ids = (const float*)d_in[0];
    const float* fc_W      = (const float*)d_in[1];
    const float* fc_b      = (const float*)d_in[2];
    const float* in_proj_W = (const float*)d_in[3];
    const float* conv_W    = (const float*)d_in[4];
    const float* conv_b    = (const float*)d_in[5];
    const float* x_proj_W  = (const float*)d_in[6];
    const float* dt_proj_W = (const float*)d_in[7];
    const float* dt_proj_b = (const float*)d_in[8];
    const float* A_log     = (const float*)d_in[9];
    const float* Dp        = (const float*)d_in[10];
    const float* out_proj_W= (const float*)d_in[11];
    const float* norm_W    = (const float*)d_in[12];
    const float* normf_W   = (const float*)d_in[13];
    const float* head_W    = (const float*)d_in[14];
    float* out = (float*)d_out;

    float* ws       = (float*)d_ws;
    float* x_ws     = ws;                                    // M*384
    float* xz_ws    = x_ws    + (size_t)MROWS * D_MODEL;     // M*1536
    float* u_ws     = xz_ws   + (size_t)MROWS * 2 * D_INNER; // M*768
    float* xdbl_ws  = u_ws    + (size_t)MROWS * D_INNER;     // M*56
    float* delta_ws = xdbl_ws + (size_t)MROWS * XPROJ_N;     // M*768
    float* y_ws     = delta_ws+ (size_t)MROWS * D_INNER;     // M*768

    const dim3 blk(256);

    // x = input_ids @ fc_W.T + fc_b   (split-K=4 -> 768 blocks, atomic)
    hipMemsetAsync(x_ws, 0, (size_t)MROWS * D_MODEL * sizeof(float), stream);
    gemm_bt<1, false, true, false><<<dim3(D_MODEL / BN, MROWS / BM, 4), blk, 0, stream>>>(
        input_ids, fc_W, fc_b, nullptr, nullptr, x_ws,
        MROWS, D_MODEL, VOCAB, VOCAB, 0, D_MODEL, 388);

    for (int i = 0; i < N_LAYER; ++i) {
        // xz = rmsnorm(x, norm_W) @ in_proj_W.T   (768 blocks, rmsnorm fused)
        gemm_bt<0, false, false, true><<<dim3(2 * D_INNER / BN, MROWS / BM, 1), blk, 0, stream>>>(
            x_ws, in_proj_W + (size_t)i * 2 * D_INNER * D_MODEL, nullptr, nullptr,
            norm_W + i * D_MODEL, xz_ws,
            MROWS, 2 * D_INNER, D_MODEL, D_MODEL, 0, 2 * D_INNER, D_MODEL);

        // u = silu(conv(xz[:, :768]) + conv_b)
        conv_silu_k<<<(MROWS * (D_INNER / 4) + 255) / 256, blk, 0, stream>>>(
            xz_ws, conv_W + (size_t)i * D_INNER * D_CONV, conv_b + i * D_INNER, u_ws);

        // x_dbl = u @ x_proj_W[i].T  (split-K=6, atomic into zeroed xdbl)
        hipMemsetAsync(xdbl_ws, 0, (size_t)MROWS * XPROJ_N * sizeof(float), stream);
        gemm_bt<0, false, true, false><<<dim3(1, MROWS / BM, 6), blk, 0, stream>>>(
            u_ws, x_proj_W + (size_t)i * XPROJ_N * D_INNER, nullptr, nullptr, nullptr,
            xdbl_ws, MROWS, XPROJ_N, D_INNER, D_INNER, 0, XPROJ_N, 128);

        // delta = softplus(x_dbl[:, :24] @ dt_proj_W[i].T + dt_proj_b[i])
        gemm_bt<2, false, false, false><<<dim3(D_INNER / BN, MROWS / BM, 1), blk, 0, stream>>>(
            xdbl_ws, dt_proj_W + (size_t)i * D_INNER * DT_RANK,
            dt_proj_b + i * D_INNER, nullptr, nullptr,
            delta_ws, MROWS, D_INNER, DT_RANK, XPROJ_N, 0, D_INNER, DT_RANK);

        // selective scan
        scan_k<<<B_ * (D_INNER / 16), blk, 0, stream>>>(
            delta_ws, u_ws, xdbl_ws, A_log + (size_t)i * D_INNER * N_STATE,
            Dp + i * D_INNER, y_ws);

        // x += (y * silu(res)) @ out_proj_W.T  (gated A, split-K=2, atomic residual)
        gemm_bt<0, true, true, false><<<dim3(D_MODEL / BN, MROWS / BM, 2), blk, 0, stream>>>(
            y_ws, out_proj_W + (size_t)i * D_MODEL * D_INNER, nullptr, xz_ws + D_INNER,
            nullptr, x_ws, MROWS, D_MODEL, D_INNER, D_INNER, 2 * D_INNER, D_MODEL, 384);
    }

    // out = rmsnorm(x, normf_W) @ head_W.T  (768 blocks, rmsnorm fused)
    gemm_bt<0, false, false, true><<<dim3(FEAT / BN, MROWS / BM, 1), blk, 0, stream>>>(
        x_ws, head_W, nullptr, nullptr, normf_W, out,
        MROWS, FEAT, D_MODEL, D_MODEL, 0, FEAT, D_MODEL);
}

// Round 7
// 883.756 us; speedup vs baseline: 1.8386x; 1.3181x over previous
//
#include <hip/hip_runtime.h>
#include <math.h>

// Problem dims
#define B_ 4
#define L_ 512
#define MROWS 2048
#define D_MODEL 384
#define N_LAYER 4
#define D_INNER 768
#define N_STATE 16
#define DT_RANK 24
#define D_CONV 4
#define VOCAB 1544
#define FEAT 1536
#define XPROJ_N 56

typedef __attribute__((ext_vector_type(8))) short short8;
typedef __attribute__((ext_vector_type(4))) float floatx4;

__device__ __forceinline__ float softplus_f(float x) { return x > 20.f ? x : log1pf(expf(x)); }
__device__ __forceinline__ float silu_f(float x) { return x / (1.f + __expf(-x)); }

// f32 -> bf16 (RNE), two packed into one u32
__device__ __forceinline__ unsigned pack2bf(float x, float y) {
    unsigned ux = __float_as_uint(x); ux = (ux + 0x7FFFu + ((ux >> 16) & 1u)) >> 16;
    unsigned uy = __float_as_uint(y); uy = (uy + 0x7FFFu + ((uy >> 16) & 1u)) >> 16;
    return ux | (uy << 16);
}

// DPP row-rotate add: x + (x rotated by N within each 16-lane row).
template <int CTRL>
__device__ __forceinline__ float dpp_radd(float x) {
    int r = __builtin_amdgcn_update_dpp(0, __float_as_int(x), CTRL, 0xf, 0xf, true);
    return x + __int_as_float(r);
}

__device__ __forceinline__ float4 ld4_guard(const float* __restrict__ p, int k, int ke) {
    if (k + 3 < ke) return *(const float4*)(p + k);
    float4 r = make_float4(0.f, 0.f, 0.f, 0.f);
    if (k + 0 < ke) r.x = p[k + 0];
    if (k + 1 < ke) r.y = p[k + 1];
    if (k + 2 < ke) r.z = p[k + 2];
    return r;
}

// ---------------------------------------------------------------------------
// MFMA bf16 GEMM: C[m,n] (+)= sum_k A[m,k]*W[n,k]  (A f32 MxK, W f32 NxK).
// Staging converts f32->bf16 (RNE). 64x64 block tile, 4 waves, each wave a
// 32x32 quadrant = 2x2 of v_mfma_f32_16x16x32_bf16; K-step 32, dbuf LDS.
// Layouts (verified m89/m91/m120): A/B frag X[row=lane&15][k=quad*8+j],
// D row=quad*4+reg, col=lane&15 (first operand rows -> D rows).
// EPI: 0 none, 1 +bias (z==0 if ATOMIC). GATED: A *= silu(gate).
// RMSN: A rows scaled rsqrt(mean A^2+1e-5)*nw[k] (full-K sites only).
// M, N multiples of 64; K arbitrary (staging zero-fills past ke).
// LDS row stride 40 shorts = 80B: 16B-aligned b128, 2-way bank alias (free).
// ---------------------------------------------------------------------------
#define ASTR 40

template <int EPI, bool GATED, bool ATOMIC, bool RMSN>
__global__ __launch_bounds__(256) void mfma_gemm(
    const float* __restrict__ A, const float* __restrict__ W,
    const float* __restrict__ bias, const float* __restrict__ gate,
    const float* __restrict__ nw,
    float* __restrict__ C, int M, int N, int K, int lda, int ldg, int ldc, int KC)
{
    __shared__ short As[2][64 * ASTR];
    __shared__ short Ws[2][64 * ASTR];
    __shared__ float sscale[64];

    const int t  = threadIdx.x;
    const int m0 = blockIdx.y * 64;
    const int n0 = blockIdx.x * 64;
    const int ks = blockIdx.z * KC;
    const int ke = min(K, ks + KC);

    const int srow = t >> 2;           // 0..63
    const int sseg = (t & 3) * 8;      // 0,8,16,24

    if (RMSN) {
        const int row = t >> 2, q = t & 3;
        const float* xr = A + (size_t)(m0 + row) * lda + q * (K >> 2);
        float s = 0.f;
        for (int i = 0; i < (K >> 2); i += 4) {
            float4 v = *(const float4*)(xr + i);
            s += v.x * v.x + v.y * v.y + v.z * v.z + v.w * v.w;
        }
        s += __shfl_xor(s, 1, 64);
        s += __shfl_xor(s, 2, 64);
        if (q == 0) sscale[row] = rsqrtf(s / (float)K + 1e-5f);
        __syncthreads();
    }

    float4 ra0, ra1, rw0, rw1, rg0, rg1, rn0, rn1;

    auto prefetch = [&](int k0) {
        const float* ar = A + (size_t)(m0 + srow) * lda;
        ra0 = ld4_guard(ar, k0 + sseg, ke);
        ra1 = ld4_guard(ar, k0 + sseg + 4, ke);
        if (GATED) {
            const float* gr = gate + (size_t)(m0 + srow) * ldg;
            rg0 = ld4_guard(gr, k0 + sseg, ke);
            rg1 = ld4_guard(gr, k0 + sseg + 4, ke);
        }
        if (RMSN) {
            rn0 = ld4_guard(nw, k0 + sseg, ke);
            rn1 = ld4_guard(nw, k0 + sseg + 4, ke);
        }
        const float* wr = W + (size_t)(n0 + srow) * (size_t)K;
        rw0 = ld4_guard(wr, k0 + sseg, ke);
        rw1 = ld4_guard(wr, k0 + sseg + 4, ke);
    };

    auto stage = [&](int p) {
        float4 a0 = ra0, a1 = ra1;
        if (GATED) {
            a0.x *= silu_f(rg0.x); a0.y *= silu_f(rg0.y); a0.z *= silu_f(rg0.z); a0.w *= silu_f(rg0.w);
            a1.x *= silu_f(rg1.x); a1.y *= silu_f(rg1.y); a1.z *= silu_f(rg1.z); a1.w *= silu_f(rg1.w);
        }
        if (RMSN) {
            float sc = sscale[srow];
            a0.x *= sc * rn0.x; a0.y *= sc * rn0.y; a0.z *= sc * rn0.z; a0.w *= sc * rn0.w;
            a1.x *= sc * rn1.x; a1.y *= sc * rn1.y; a1.z *= sc * rn1.z; a1.w *= sc * rn1.w;
        }
        int4 pa;
        pa.x = pack2bf(a0.x, a0.y); pa.y = pack2bf(a0.z, a0.w);
        pa.z = pack2bf(a1.x, a1.y); pa.w = pack2bf(a1.z, a1.w);
        *(int4*)&As[p][srow * ASTR + sseg] = pa;
        int4 pw;
        pw.x = pack2bf(rw0.x, rw0.y); pw.y = pack2bf(rw0.z, rw0.w);
        pw.z = pack2bf(rw1.x, rw1.y); pw.w = pack2bf(rw1.z, rw1.w);
        *(int4*)&Ws[p][srow * ASTR + sseg] = pw;
    };

    prefetch(ks);
    stage(0);
    __syncthreads();

    floatx4 acc[2][2];
#pragma unroll
    for (int i = 0; i < 2; ++i)
#pragma unroll
        for (int j = 0; j < 2; ++j) acc[i][j] = (floatx4){0.f, 0.f, 0.f, 0.f};

    const int w    = t >> 6;
    const int lane = t & 63;
    const int quad = lane >> 4;
    const int lm   = lane & 15;
    const int aoff = ((w >> 1) * 32 + lm) * ASTR + quad * 8;
    const int boff = ((w & 1) * 32 + lm) * ASTR + quad * 8;

    int p = 0;
    for (int k0 = ks; k0 < ke; k0 += 32) {
        const bool more = (k0 + 32 < ke);
        if (more) prefetch(k0 + 32);
        short8 a0 = *(const short8*)&As[p][aoff];
        short8 a1 = *(const short8*)&As[p][aoff + 16 * ASTR];
        short8 b0 = *(const short8*)&Ws[p][boff];
        short8 b1 = *(const short8*)&Ws[p][boff + 16 * ASTR];
        acc[0][0] = __builtin_amdgcn_mfma_f32_16x16x32_bf16(a0, b0, acc[0][0], 0, 0, 0);
        acc[0][1] = __builtin_amdgcn_mfma_f32_16x16x32_bf16(a0, b1, acc[0][1], 0, 0, 0);
        acc[1][0] = __builtin_amdgcn_mfma_f32_16x16x32_bf16(a1, b0, acc[1][0], 0, 0, 0);
        acc[1][1] = __builtin_amdgcn_mfma_f32_16x16x32_bf16(a1, b1, acc[1][1], 0, 0, 0);
        if (more) {
            stage(p ^ 1);
            __syncthreads();
            p ^= 1;
        }
    }

    const int rbase = m0 + (w >> 1) * 32 + quad * 4;
    const int cbase = n0 + (w & 1) * 32 + lm;
#pragma unroll
    for (int mt = 0; mt < 2; ++mt)
#pragma unroll
        for (int nt = 0; nt < 2; ++nt) {
            const int gc = cbase + nt * 16;
#pragma unroll
            for (int r = 0; r < 4; ++r) {
                const size_t gr = rbase + mt * 16 + r;
                float v = acc[mt][nt][r];
                if (ATOMIC) {
                    if (EPI == 1 && blockIdx.z == 0) v += bias[gc];
                    atomicAdd(&C[gr * ldc + gc], v);
                } else {
                    if (EPI == 1) v += bias[gc];
                    C[gr * ldc + gc] = v;
                }
            }
        }
}

// ---------------------------------------------------------------------------
// f32 tiled GEMM (kept for the numerically-sensitive delta path).
// ---------------------------------------------------------------------------
#define BM 64
#define BN 64
#define BK 16

template <int EPI, bool ATOMIC>
__global__ __launch_bounds__(256) void gemm_bt(
    const float* __restrict__ A, const float* __restrict__ W,
    const float* __restrict__ bias,
    float* __restrict__ C, int M, int N, int K, int lda, int ldc, int KC)
{
    __shared__ float Asf[2][BK][BM + 4];
    __shared__ float Wsf[2][BK][BN + 4];
    const int t  = threadIdx.x;
    const int tx = t & 15;
    const int ty = t >> 4;
    const int m0 = blockIdx.y * BM;
    const int n0 = blockIdx.x * BN;
    const int ks = blockIdx.z * KC;
    const int ke = min(K, ks + KC);

    const int sr = t >> 2;
    const int sc = (t & 3) << 2;
    const int gm = m0 + sr;
    const int gn = n0 + sr;

    float4 ra = make_float4(0.f, 0.f, 0.f, 0.f), rw = ra;

    auto prefetch = [&](int k0) {
        ra = make_float4(0.f, 0.f, 0.f, 0.f);
        rw = ra;
        if (gm < M) ra = ld4_guard(A + (size_t)gm * lda, k0 + sc, ke);
        if (gn < N) rw = ld4_guard(W + (size_t)gn * (size_t)K, k0 + sc, ke);
    };
    auto stage = [&](int p) {
        Asf[p][sc + 0][sr] = ra.x; Asf[p][sc + 1][sr] = ra.y;
        Asf[p][sc + 2][sr] = ra.z; Asf[p][sc + 3][sr] = ra.w;
        Wsf[p][sc + 0][sr] = rw.x; Wsf[p][sc + 1][sr] = rw.y;
        Wsf[p][sc + 2][sr] = rw.z; Wsf[p][sc + 3][sr] = rw.w;
    };

    prefetch(ks);
    stage(0);
    __syncthreads();

    float acc[4][4] = {};
    int p = 0;

    for (int k0 = ks; k0 < ke; k0 += BK) {
        const bool more = (k0 + BK < ke);
        if (more) prefetch(k0 + BK);
#pragma unroll
        for (int kk = 0; kk < BK; ++kk) {
            float a[4], b[4];
#pragma unroll
            for (int i = 0; i < 4; ++i) a[i] = Asf[p][kk][ty * 4 + i];
#pragma unroll
            for (int j = 0; j < 4; ++j) b[j] = Wsf[p][kk][tx * 4 + j];
#pragma unroll
            for (int i = 0; i < 4; ++i)
#pragma unroll
                for (int j = 0; j < 4; ++j) acc[i][j] = fmaf(a[i], b[j], acc[i][j]);
        }
        if (more) {
            stage(p ^ 1);
            __syncthreads();
            p ^= 1;
        }
    }

#pragma unroll
    for (int i = 0; i < 4; ++i) {
        int om = m0 + ty * 4 + i;
        if (om >= M) continue;
#pragma unroll
        for (int j = 0; j < 4; ++j) {
            int on = n0 + tx * 4 + j;
            if (on >= N) continue;
            float v = acc[i][j];
            if (ATOMIC) {
                atomicAdd(&C[(size_t)om * ldc + on], v);
            } else {
                if (EPI == 2) v = softplus_f(v + bias[on]);
                C[(size_t)om * ldc + on] = v;
            }
        }
    }
}

// ---------------------------------------------------------------------------
// Depthwise causal conv (width 4) + bias + SiLU, float4 over channels.
// ---------------------------------------------------------------------------
__global__ __launch_bounds__(256) void conv_silu_k(
    const float* __restrict__ xz, const float* __restrict__ w,
    const float* __restrict__ cb, float* __restrict__ u)
{
    int idx = blockIdx.x * 256 + threadIdx.x;
    if (idx >= MROWS * (D_INNER / 4)) return;
    int dq = idx % (D_INNER / 4);
    int m  = idx / (D_INNER / 4);
    int d0 = dq * 4;
    int b = m / L_, l = m % L_;
    float4 wq[4];
#pragma unroll
    for (int j = 0; j < 4; ++j) wq[j] = *(const float4*)(w + (d0 + j) * D_CONV);
    float acc[4];
#pragma unroll
    for (int j = 0; j < 4; ++j) acc[j] = cb[d0 + j];
#pragma unroll
    for (int tt = 0; tt < 4; ++tt) {
        int ll = l - 3 + tt;
        if (ll >= 0) {
            float4 xv = *(const float4*)(xz + (size_t)(b * L_ + ll) * (2 * D_INNER) + d0);
            acc[0] = fmaf(xv.x, ((const float*)&wq[0])[tt], acc[0]);
            acc[1] = fmaf(xv.y, ((const float*)&wq[1])[tt], acc[1]);
            acc[2] = fmaf(xv.z, ((const float*)&wq[2])[tt], acc[2]);
            acc[3] = fmaf(xv.w, ((const float*)&wq[3])[tt], acc[3]);
        }
    }
    float4 o = make_float4(silu_f(acc[0]), silu_f(acc[1]), silu_f(acc[2]), silu_f(acc[3]));
    *(float4*)(u + (size_t)m * D_INNER + d0) = o;
}

// ---------------------------------------------------------------------------
// Selective scan, LDS-chunked (64 steps). Block = 16 d x 16 n.
// ---------------------------------------------------------------------------
#define SCH 64
__global__ __launch_bounds__(256) void scan_k(
    const float* __restrict__ delta, const float* __restrict__ u,
    const float* __restrict__ xdbl, const float* __restrict__ A_log,
    const float* __restrict__ Dp, float* __restrict__ y)
{
    __shared__ float sd[SCH][16], su[SCH][16], sB[SCH][16], sC[SCH][16];
    const int t  = threadIdx.x;
    const int n  = t & 15;
    const int dl = t >> 4;
    const int b  = blockIdx.x / (D_INNER / 16);
    const int dg = blockIdx.x % (D_INNER / 16);
    const int d  = dg * 16 + dl;

    const float Av = -expf(A_log[d * N_STATE + n]);
    const float Dd = Dp[d];
    const int lr = t >> 2;
    const int lc = (t & 3) << 2;
    float h = 0.f;

    for (int c0 = 0; c0 < L_; c0 += SCH) {
        const size_t mrow = (size_t)b * L_ + c0 + lr;
        const float4 vd = *(const float4*)(delta + mrow * D_INNER + dg * 16 + lc);
        const float4 vu = *(const float4*)(u     + mrow * D_INNER + dg * 16 + lc);
        const float4 vB = *(const float4*)(xdbl  + mrow * XPROJ_N + DT_RANK + lc);
        const float4 vC = *(const float4*)(xdbl  + mrow * XPROJ_N + DT_RANK + N_STATE + lc);
        __syncthreads();
        *(float4*)&sd[lr][lc] = vd;
        *(float4*)&su[lr][lc] = vu;
        *(float4*)&sB[lr][lc] = vB;
        *(float4*)&sC[lr][lc] = vC;
        __syncthreads();
#pragma unroll 8
        for (int j = 0; j < SCH; ++j) {
            float dv = sd[j][dl];
            float uv = su[j][dl];
            float e  = __expf(dv * Av);
            float c  = dv * uv * sB[j][n];
            h = fmaf(e, h, c);
            float p = h * sC[j][n];
            p = dpp_radd<0x128>(p);
            p = dpp_radd<0x124>(p);
            p = dpp_radd<0x122>(p);
            p = dpp_radd<0x121>(p);
            if (n == 0) y[((size_t)b * L_ + c0 + j) * D_INNER + d] = fmaf(uv, Dd, p);
        }
    }
}

// ---------------------------------------------------------------------------
extern "C" void kernel_launch(void* const* d_in, const int* in_sizes, int n_in,
                              void* d_out, int out_size, void* d_ws, size_t ws_size,
                              hipStream_t stream)
{
    const float* input_ids = (const float*)d_in[0];
    const float* fc_W      = (const float*)d_in[1];
    const float* fc_b      = (const float*)d_in[2];
    const float* in_proj_W = (const float*)d_in[3];
    const float* conv_W    = (const float*)d_in[4];
    const float* conv_b    = (const float*)d_in[5];
    const float* x_proj_W  = (const float*)d_in[6];
    const float* dt_proj_W = (const float*)d_in[7];
    const float* dt_proj_b = (const float*)d_in[8];
    const float* A_log     = (const float*)d_in[9];
    const float* Dp        = (const float*)d_in[10];
    const float* out_proj_W= (const float*)d_in[11];
    const float* norm_W    = (const float*)d_in[12];
    const float* normf_W   = (const float*)d_in[13];
    const float* head_W    = (const float*)d_in[14];
    float* out = (float*)d_out;

    float* ws       = (float*)d_ws;
    float* x_ws     = ws;                                    // M*384
    float* xz_ws    = x_ws    + (size_t)MROWS * D_MODEL;     // M*1536
    float* u_ws     = xz_ws   + (size_t)MROWS * 2 * D_INNER; // M*768
    float* xdbl_ws  = u_ws    + (size_t)MROWS * D_INNER;     // M*56
    float* delta_ws = xdbl_ws + (size_t)MROWS * XPROJ_N;     // M*768
    float* y_ws     = delta_ws+ (size_t)MROWS * D_INNER;     // M*768

    const dim3 blk(256);

    // x = input_ids @ fc_W.T + fc_b   (MFMA, split-K=4, atomic into zeroed x)
    hipMemsetAsync(x_ws, 0, (size_t)MROWS * D_MODEL * sizeof(float), stream);
    mfma_gemm<1, false, true, false><<<dim3(D_MODEL / 64, MROWS / 64, 4), blk, 0, stream>>>(
        input_ids, fc_W, fc_b, nullptr, nullptr, x_ws,
        MROWS, D_MODEL, VOCAB, VOCAB, 0, D_MODEL, 416);

    for (int i = 0; i < N_LAYER; ++i) {
        // xz = rmsnorm(x, norm_W) @ in_proj_W.T   (MFMA, rmsnorm fused)
        mfma_gemm<0, false, false, true><<<dim3(2 * D_INNER / 64, MROWS / 64, 1), blk, 0, stream>>>(
            x_ws, in_proj_W + (size_t)i * 2 * D_INNER * D_MODEL, nullptr, nullptr,
            norm_W + i * D_MODEL, xz_ws,
            MROWS, 2 * D_INNER, D_MODEL, D_MODEL, 0, 2 * D_INNER, D_MODEL);

        // u = silu(conv(xz[:, :768]) + conv_b)
        conv_silu_k<<<(MROWS * (D_INNER / 4) + 255) / 256, blk, 0, stream>>>(
            xz_ws, conv_W + (size_t)i * D_INNER * D_CONV, conv_b + i * D_INNER, u_ws);

        // x_dbl = u @ x_proj_W[i].T  (f32, split-K=6, atomic into zeroed xdbl)
        hipMemsetAsync(xdbl_ws, 0, (size_t)MROWS * XPROJ_N * sizeof(float), stream);
        gemm_bt<0, true><<<dim3(1, MROWS / BM, 6), blk, 0, stream>>>(
            u_ws, x_proj_W + (size_t)i * XPROJ_N * D_INNER, nullptr,
            xdbl_ws, MROWS, XPROJ_N, D_INNER, D_INNER, XPROJ_N, 128);

        // delta = softplus(x_dbl[:, :24] @ dt_proj_W[i].T + dt_proj_b[i])  (f32)
        gemm_bt<2, false><<<dim3(D_INNER / BN, MROWS / BM, 1), blk, 0, stream>>>(
            xdbl_ws, dt_proj_W + (size_t)i * D_INNER * DT_RANK,
            dt_proj_b + i * D_INNER,
            delta_ws, MROWS, D_INNER, DT_RANK, XPROJ_N, D_INNER, DT_RANK);

        // selective scan
        scan_k<<<B_ * (D_INNER / 16), blk, 0, stream>>>(
            delta_ws, u_ws, xdbl_ws, A_log + (size_t)i * D_INNER * N_STATE,
            Dp + i * D_INNER, y_ws);

        // x += (y * silu(res)) @ out_proj_W.T  (MFMA, gated A, split-K=2, atomic)
        mfma_gemm<0, true, true, false><<<dim3(D_MODEL / 64, MROWS / 64, 2), blk, 0, stream>>>(
            y_ws, out_proj_W + (size_t)i * D_MODEL * D_INNER, nullptr, xz_ws + D_INNER,
            nullptr, x_ws, MROWS, D_MODEL, D_INNER, D_INNER, 2 * D_INNER, D_MODEL, 384);
    }

    // out = rmsnorm(x, normf_W) @ head_W.T  (MFMA, rmsnorm fused)
    mfma_gemm<0, false, false, true><<<dim3(FEAT / 64, MROWS / 64, 1), blk, 0, stream>>>(
        x_ws, head_W, nullptr, nullptr, normf_W, out,
        MROWS, FEAT, D_MODEL, D_MODEL, 0, FEAT, D_MODEL);
}

// Round 8
// 759.911 us; speedup vs baseline: 2.1383x; 1.1630x over previous
//
#include <hip/hip_runtime.h>
#include <math.h>

// Problem dims
#define B_ 4
#define L_ 512
#define MROWS 2048
#define D_MODEL 384
#define N_LAYER 4
#define D_INNER 768
#define N_STATE 16
#define DT_RANK 24
#define D_CONV 4
#define VOCAB 1544
#define FEAT 1536
#define XPROJ_N 56
#define NCH 8               // scan chunks per batch (L/64)
#define SCH 64              // scan chunk length

typedef __attribute__((ext_vector_type(8))) short short8;
typedef __attribute__((ext_vector_type(4))) float floatx4;

__device__ __forceinline__ float softplus_f(float x) { return x > 20.f ? x : log1pf(expf(x)); }
__device__ __forceinline__ float silu_f(float x) { return x / (1.f + __expf(-x)); }

// f32 -> bf16 (RNE), two packed into one u32
__device__ __forceinline__ unsigned pack2bf(float x, float y) {
    unsigned ux = __float_as_uint(x); ux = (ux + 0x7FFFu + ((ux >> 16) & 1u)) >> 16;
    unsigned uy = __float_as_uint(y); uy = (uy + 0x7FFFu + ((uy >> 16) & 1u)) >> 16;
    return ux | (uy << 16);
}

// DPP row-rotate add: x + (x rotated by N within each 16-lane row).
template <int CTRL>
__device__ __forceinline__ float dpp_radd(float x) {
    int r = __builtin_amdgcn_update_dpp(0, __float_as_int(x), CTRL, 0xf, 0xf, true);
    return x + __int_as_float(r);
}

__device__ __forceinline__ float4 ld4_guard(const float* __restrict__ p, int k, int ke) {
    if (k + 3 < ke) return *(const float4*)(p + k);
    float4 r = make_float4(0.f, 0.f, 0.f, 0.f);
    if (k + 0 < ke) r.x = p[k + 0];
    if (k + 1 < ke) r.y = p[k + 1];
    if (k + 2 < ke) r.z = p[k + 2];
    return r;
}

// ---------------------------------------------------------------------------
// MFMA bf16 GEMM: C[m,n] (+)= sum_k A[m,k]*W[n,k]  (A f32 MxK, W f32 NxK).
// 64x64 tile, 4 waves, each a 32x32 quadrant = 2x2 v_mfma_f32_16x16x32_bf16.
// NG: guard W rows / C cols >= N (for N=56 x_proj).
// ---------------------------------------------------------------------------
#define ASTR 40

template <int EPI, bool GATED, bool ATOMIC, bool RMSN, bool NG>
__global__ __launch_bounds__(256) void mfma_gemm(
    const float* __restrict__ A, const float* __restrict__ W,
    const float* __restrict__ bias, const float* __restrict__ gate,
    const float* __restrict__ nw,
    float* __restrict__ C, int M, int N, int K, int lda, int ldg, int ldc, int KC)
{
    __shared__ short As[2][64 * ASTR];
    __shared__ short Ws[2][64 * ASTR];
    __shared__ float sscale[64];

    const int t  = threadIdx.x;
    const int m0 = blockIdx.y * 64;
    const int n0 = blockIdx.x * 64;
    const int ks = blockIdx.z * KC;
    const int ke = min(K, ks + KC);

    const int srow = t >> 2;           // 0..63
    const int sseg = (t & 3) * 8;      // 0,8,16,24

    if (RMSN) {
        const int row = t >> 2, q = t & 3;
        const float* xr = A + (size_t)(m0 + row) * lda + q * (K >> 2);
        float s = 0.f;
        for (int i = 0; i < (K >> 2); i += 4) {
            float4 v = *(const float4*)(xr + i);
            s += v.x * v.x + v.y * v.y + v.z * v.z + v.w * v.w;
        }
        s += __shfl_xor(s, 1, 64);
        s += __shfl_xor(s, 2, 64);
        if (q == 0) sscale[row] = rsqrtf(s / (float)K + 1e-5f);
        __syncthreads();
    }

    float4 ra0, ra1, rw0, rw1, rg0, rg1, rn0, rn1;

    auto prefetch = [&](int k0) {
        const float* ar = A + (size_t)(m0 + srow) * lda;
        ra0 = ld4_guard(ar, k0 + sseg, ke);
        ra1 = ld4_guard(ar, k0 + sseg + 4, ke);
        if (GATED) {
            const float* gr = gate + (size_t)(m0 + srow) * ldg;
            rg0 = ld4_guard(gr, k0 + sseg, ke);
            rg1 = ld4_guard(gr, k0 + sseg + 4, ke);
        }
        if (RMSN) {
            rn0 = ld4_guard(nw, k0 + sseg, ke);
            rn1 = ld4_guard(nw, k0 + sseg + 4, ke);
        }
        if (!NG || (n0 + srow) < N) {
            const float* wr = W + (size_t)(n0 + srow) * (size_t)K;
            rw0 = ld4_guard(wr, k0 + sseg, ke);
            rw1 = ld4_guard(wr, k0 + sseg + 4, ke);
        } else {
            rw0 = make_float4(0.f, 0.f, 0.f, 0.f);
            rw1 = rw0;
        }
    };

    auto stage = [&](int p) {
        float4 a0 = ra0, a1 = ra1;
        if (GATED) {
            a0.x *= silu_f(rg0.x); a0.y *= silu_f(rg0.y); a0.z *= silu_f(rg0.z); a0.w *= silu_f(rg0.w);
            a1.x *= silu_f(rg1.x); a1.y *= silu_f(rg1.y); a1.z *= silu_f(rg1.z); a1.w *= silu_f(rg1.w);
        }
        if (RMSN) {
            float sc = sscale[srow];
            a0.x *= sc * rn0.x; a0.y *= sc * rn0.y; a0.z *= sc * rn0.z; a0.w *= sc * rn0.w;
            a1.x *= sc * rn1.x; a1.y *= sc * rn1.y; a1.z *= sc * rn1.z; a1.w *= sc * rn1.w;
        }
        int4 pa;
        pa.x = pack2bf(a0.x, a0.y); pa.y = pack2bf(a0.z, a0.w);
        pa.z = pack2bf(a1.x, a1.y); pa.w = pack2bf(a1.z, a1.w);
        *(int4*)&As[p][srow * ASTR + sseg] = pa;
        int4 pw;
        pw.x = pack2bf(rw0.x, rw0.y); pw.y = pack2bf(rw0.z, rw0.w);
        pw.z = pack2bf(rw1.x, rw1.y); pw.w = pack2bf(rw1.z, rw1.w);
        *(int4*)&Ws[p][srow * ASTR + sseg] = pw;
    };

    prefetch(ks);
    stage(0);
    __syncthreads();

    floatx4 acc[2][2];
#pragma unroll
    for (int i = 0; i < 2; ++i)
#pragma unroll
        for (int j = 0; j < 2; ++j) acc[i][j] = (floatx4){0.f, 0.f, 0.f, 0.f};

    const int w    = t >> 6;
    const int lane = t & 63;
    const int quad = lane >> 4;
    const int lm   = lane & 15;
    const int aoff = ((w >> 1) * 32 + lm) * ASTR + quad * 8;
    const int boff = ((w & 1) * 32 + lm) * ASTR + quad * 8;

    int p = 0;
    for (int k0 = ks; k0 < ke; k0 += 32) {
        const bool more = (k0 + 32 < ke);
        if (more) prefetch(k0 + 32);
        short8 a0 = *(const short8*)&As[p][aoff];
        short8 a1 = *(const short8*)&As[p][aoff + 16 * ASTR];
        short8 b0 = *(const short8*)&Ws[p][boff];
        short8 b1 = *(const short8*)&Ws[p][boff + 16 * ASTR];
        acc[0][0] = __builtin_amdgcn_mfma_f32_16x16x32_bf16(a0, b0, acc[0][0], 0, 0, 0);
        acc[0][1] = __builtin_amdgcn_mfma_f32_16x16x32_bf16(a0, b1, acc[0][1], 0, 0, 0);
        acc[1][0] = __builtin_amdgcn_mfma_f32_16x16x32_bf16(a1, b0, acc[1][0], 0, 0, 0);
        acc[1][1] = __builtin_amdgcn_mfma_f32_16x16x32_bf16(a1, b1, acc[1][1], 0, 0, 0);
        if (more) {
            stage(p ^ 1);
            __syncthreads();
            p ^= 1;
        }
    }

    const int rbase = m0 + (w >> 1) * 32 + quad * 4;
    const int cbase = n0 + (w & 1) * 32 + lm;
#pragma unroll
    for (int mt = 0; mt < 2; ++mt)
#pragma unroll
        for (int nt = 0; nt < 2; ++nt) {
            const int gc = cbase + nt * 16;
            if (NG && gc >= N) continue;
#pragma unroll
            for (int r = 0; r < 4; ++r) {
                const size_t gr = rbase + mt * 16 + r;
                float v = acc[mt][nt][r];
                if (ATOMIC) {
                    if (EPI == 1 && blockIdx.z == 0) v += bias[gc];
                    atomicAdd(&C[gr * ldc + gc], v);
                } else {
                    if (EPI == 1) v += bias[gc];
                    C[gr * ldc + gc] = v;
                }
            }
        }
}

// ---------------------------------------------------------------------------
// f32 tiled GEMM (delta path only: dt_proj, K=24, softplus epilogue).
// ---------------------------------------------------------------------------
#define BM 64
#define BN 64
#define BK 16

template <int EPI>
__global__ __launch_bounds__(256) void gemm_bt(
    const float* __restrict__ A, const float* __restrict__ W,
    const float* __restrict__ bias,
    float* __restrict__ C, int M, int N, int K, int lda, int ldc)
{
    __shared__ float Asf[2][BK][BM + 4];
    __shared__ float Wsf[2][BK][BN + 4];
    const int t  = threadIdx.x;
    const int tx = t & 15;
    const int ty = t >> 4;
    const int m0 = blockIdx.y * BM;
    const int n0 = blockIdx.x * BN;
    const int ke = K;

    const int sr = t >> 2;
    const int sc = (t & 3) << 2;
    const int gm = m0 + sr;
    const int gn = n0 + sr;

    float4 ra = make_float4(0.f, 0.f, 0.f, 0.f), rw = ra;

    auto prefetch = [&](int k0) {
        ra = make_float4(0.f, 0.f, 0.f, 0.f);
        rw = ra;
        if (gm < M) ra = ld4_guard(A + (size_t)gm * lda, k0 + sc, ke);
        if (gn < N) rw = ld4_guard(W + (size_t)gn * (size_t)K, k0 + sc, ke);
    };
    auto stage = [&](int p) {
        Asf[p][sc + 0][sr] = ra.x; Asf[p][sc + 1][sr] = ra.y;
        Asf[p][sc + 2][sr] = ra.z; Asf[p][sc + 3][sr] = ra.w;
        Wsf[p][sc + 0][sr] = rw.x; Wsf[p][sc + 1][sr] = rw.y;
        Wsf[p][sc + 2][sr] = rw.z; Wsf[p][sc + 3][sr] = rw.w;
    };

    prefetch(0);
    stage(0);
    __syncthreads();

    float acc[4][4] = {};
    int p = 0;

    for (int k0 = 0; k0 < ke; k0 += BK) {
        const bool more = (k0 + BK < ke);
        if (more) prefetch(k0 + BK);
#pragma unroll
        for (int kk = 0; kk < BK; ++kk) {
            float a[4], b[4];
#pragma unroll
            for (int i = 0; i < 4; ++i) a[i] = Asf[p][kk][ty * 4 + i];
#pragma unroll
            for (int j = 0; j < 4; ++j) b[j] = Wsf[p][kk][tx * 4 + j];
#pragma unroll
            for (int i = 0; i < 4; ++i)
#pragma unroll
                for (int j = 0; j < 4; ++j) acc[i][j] = fmaf(a[i], b[j], acc[i][j]);
        }
        if (more) {
            stage(p ^ 1);
            __syncthreads();
            p ^= 1;
        }
    }

#pragma unroll
    for (int i = 0; i < 4; ++i) {
        int om = m0 + ty * 4 + i;
        if (om >= M) continue;
#pragma unroll
        for (int j = 0; j < 4; ++j) {
            int on = n0 + tx * 4 + j;
            if (on >= N) continue;
            float v = acc[i][j];
            if (EPI == 2) v = softplus_f(v + bias[on]);
            C[(size_t)om * ldc + on] = v;
        }
    }
}

// ---------------------------------------------------------------------------
// Depthwise causal conv (width 4) + bias + SiLU, float4 over channels.
// ---------------------------------------------------------------------------
__global__ __launch_bounds__(256) void conv_silu_k(
    const float* __restrict__ xz, const float* __restrict__ w,
    const float* __restrict__ cb, float* __restrict__ u)
{
    int idx = blockIdx.x * 256 + threadIdx.x;
    if (idx >= MROWS * (D_INNER / 4)) return;
    int dq = idx % (D_INNER / 4);
    int m  = idx / (D_INNER / 4);
    int d0 = dq * 4;
    int b = m / L_, l = m % L_;
    float4 wq[4];
#pragma unroll
    for (int j = 0; j < 4; ++j) wq[j] = *(const float4*)(w + (d0 + j) * D_CONV);
    float acc[4];
#pragma unroll
    for (int j = 0; j < 4; ++j) acc[j] = cb[d0 + j];
#pragma unroll
    for (int tt = 0; tt < 4; ++tt) {
        int ll = l - 3 + tt;
        if (ll >= 0) {
            float4 xv = *(const float4*)(xz + (size_t)(b * L_ + ll) * (2 * D_INNER) + d0);
            acc[0] = fmaf(xv.x, ((const float*)&wq[0])[tt], acc[0]);
            acc[1] = fmaf(xv.y, ((const float*)&wq[1])[tt], acc[1]);
            acc[2] = fmaf(xv.z, ((const float*)&wq[2])[tt], acc[2]);
            acc[3] = fmaf(xv.w, ((const float*)&wq[3])[tt], acc[3]);
        }
    }
    float4 o = make_float4(silu_f(acc[0]), silu_f(acc[1]), silu_f(acc[2]), silu_f(acc[3]));
    *(float4*)(u + (size_t)m * D_INNER + d0) = o;
}

// ---------------------------------------------------------------------------
// Chunked selective scan, pass 1: local scan per 64-step chunk (h0 = 0).
// Writes y_local, per-chunk decay product P and end-state H.
// grid (48, NCH, B_), block = 16 d x 16 n.
// ---------------------------------------------------------------------------
__global__ __launch_bounds__(256) void scan1_k(
    const float* __restrict__ delta, const float* __restrict__ u,
    const float* __restrict__ xdbl, const float* __restrict__ A_log,
    const float* __restrict__ Dp, float* __restrict__ y,
    float* __restrict__ Pws, float* __restrict__ Hws)
{
    __shared__ float sd[SCH][16], su[SCH][16], sB[SCH][16], sC[SCH][16];
    const int t  = threadIdx.x;
    const int n  = t & 15;
    const int dl = t >> 4;
    const int dg = blockIdx.x;
    const int c  = blockIdx.y;
    const int b  = blockIdx.z;
    const int d  = dg * 16 + dl;
    const int l0 = c * SCH;

    const float Av = -expf(A_log[d * N_STATE + n]);
    const float Dd = Dp[d];
    const int lr = t >> 2;
    const int lc = (t & 3) << 2;

    {
        const size_t mrow = (size_t)b * L_ + l0 + lr;
        *(float4*)&sd[lr][lc] = *(const float4*)(delta + mrow * D_INNER + dg * 16 + lc);
        *(float4*)&su[lr][lc] = *(const float4*)(u     + mrow * D_INNER + dg * 16 + lc);
        *(float4*)&sB[lr][lc] = *(const float4*)(xdbl  + mrow * XPROJ_N + DT_RANK + lc);
        *(float4*)&sC[lr][lc] = *(const float4*)(xdbl  + mrow * XPROJ_N + DT_RANK + N_STATE + lc);
    }
    __syncthreads();

    float h = 0.f, pacc = 1.f;
#pragma unroll 8
    for (int j = 0; j < SCH; ++j) {
        float dv = sd[j][dl];
        float uv = su[j][dl];
        float e  = __expf(dv * Av);
        float cc = dv * uv * sB[j][n];
        h = fmaf(e, h, cc);
        pacc *= e;
        float p = h * sC[j][n];
        p = dpp_radd<0x128>(p);
        p = dpp_radd<0x124>(p);
        p = dpp_radd<0x122>(p);
        p = dpp_radd<0x121>(p);
        if (n == 0) y[((size_t)b * L_ + l0 + j) * D_INNER + d] = fmaf(uv, Dd, p);
    }
    const size_t phi = (((size_t)(b * NCH + c) * D_INNER + dg * 16 + dl) << 4) + n;
    Pws[phi] = pacc;
    Hws[phi] = h;
}

// ---------------------------------------------------------------------------
// Chunked selective scan, pass 2: for chunks 1..NCH-1, combine h_start from
// (P,H) of preceding chunks, then add C_t * (prod e) * h_start to y.
// grid (48, NCH-1, B_).
// ---------------------------------------------------------------------------
__global__ __launch_bounds__(256) void scan2_k(
    const float* __restrict__ delta, const float* __restrict__ xdbl,
    const float* __restrict__ A_log,
    const float* __restrict__ Pws, const float* __restrict__ Hws,
    float* __restrict__ y)
{
    __shared__ float sd[SCH][16], sC[SCH][16];
    const int t  = threadIdx.x;
    const int n  = t & 15;
    const int dl = t >> 4;
    const int dg = blockIdx.x;
    const int c  = blockIdx.y + 1;
    const int b  = blockIdx.z;
    const int d  = dg * 16 + dl;
    const int l0 = c * SCH;

    const float Av = -expf(A_log[d * N_STATE + n]);

    // h_start = fold over chunks 0..c-1
    float hs = 0.f;
    for (int s = 0; s < c; ++s) {
        const size_t phi = (((size_t)(b * NCH + s) * D_INNER + d) << 4) + n;
        hs = fmaf(Pws[phi], hs, Hws[phi]);
    }

    const int lr = t >> 2;
    const int lc = (t & 3) << 2;
    {
        const size_t mrow = (size_t)b * L_ + l0 + lr;
        *(float4*)&sd[lr][lc] = *(const float4*)(delta + mrow * D_INNER + dg * 16 + lc);
        *(float4*)&sC[lr][lc] = *(const float4*)(xdbl  + mrow * XPROJ_N + DT_RANK + N_STATE + lc);
    }
    __syncthreads();

    float g = hs;
#pragma unroll 8
    for (int j = 0; j < SCH; ++j) {
        float dv = sd[j][dl];
        g *= __expf(dv * Av);
        float p = g * sC[j][n];
        p = dpp_radd<0x128>(p);
        p = dpp_radd<0x124>(p);
        p = dpp_radd<0x122>(p);
        p = dpp_radd<0x121>(p);
        if (n == 0) y[((size_t)b * L_ + l0 + j) * D_INNER + d] += p;
    }
}

// ---------------------------------------------------------------------------
extern "C" void kernel_launch(void* const* d_in, const int* in_sizes, int n_in,
                              void* d_out, int out_size, void* d_ws, size_t ws_size,
                              hipStream_t stream)
{
    const float* input_ids = (const float*)d_in[0];
    const float* fc_W      = (const float*)d_in[1];
    const float* fc_b      = (const float*)d_in[2];
    const float* in_proj_W = (const float*)d_in[3];
    const float* conv_W    = (const float*)d_in[4];
    const float* conv_b    = (const float*)d_in[5];
    const float* x_proj_W  = (const float*)d_in[6];
    const float* dt_proj_W = (const float*)d_in[7];
    const float* dt_proj_b = (const float*)d_in[8];
    const float* A_log     = (const float*)d_in[9];
    const float* Dp        = (const float*)d_in[10];
    const float* out_proj_W= (const float*)d_in[11];
    const float* norm_W    = (const float*)d_in[12];
    const float* normf_W   = (const float*)d_in[13];
    const float* head_W    = (const float*)d_in[14];
    float* out = (float*)d_out;

    float* ws       = (float*)d_ws;
    float* x_ws     = ws;                                    // M*384
    float* xz_ws    = x_ws    + (size_t)MROWS * D_MODEL;     // M*1536
    float* u_ws     = xz_ws   + (size_t)MROWS * 2 * D_INNER; // M*768
    float* xdbl_ws  = u_ws    + (size_t)MROWS * D_INNER;     // M*56
    float* delta_ws = xdbl_ws + (size_t)MROWS * XPROJ_N;     // M*768
    float* y_ws     = delta_ws+ (size_t)MROWS * D_INNER;     // M*768
    float* P_ws     = y_ws    + (size_t)MROWS * D_INNER;     // B*8*768*16
    float* H_ws     = P_ws    + (size_t)B_ * NCH * D_INNER * N_STATE;

    const dim3 blk(256);

    // x = input_ids @ fc_W.T + fc_b   (MFMA, split-K=4, atomic into zeroed x)
    hipMemsetAsync(x_ws, 0, (size_t)MROWS * D_MODEL * sizeof(float), stream);
    mfma_gemm<1, false, true, false, false><<<dim3(D_MODEL / 64, MROWS / 64, 4), blk, 0, stream>>>(
        input_ids, fc_W, fc_b, nullptr, nullptr, x_ws,
        MROWS, D_MODEL, VOCAB, VOCAB, 0, D_MODEL, 416);

    for (int i = 0; i < N_LAYER; ++i) {
        // xz = rmsnorm(x, norm_W) @ in_proj_W.T   (MFMA, rmsnorm fused)
        mfma_gemm<0, false, false, true, false><<<dim3(2 * D_INNER / 64, MROWS / 64, 1), blk, 0, stream>>>(
            x_ws, in_proj_W + (size_t)i * 2 * D_INNER * D_MODEL, nullptr, nullptr,
            norm_W + i * D_MODEL, xz_ws,
            MROWS, 2 * D_INNER, D_MODEL, D_MODEL, 0, 2 * D_INNER, D_MODEL);

        // u = silu(conv(xz[:, :768]) + conv_b)
        conv_silu_k<<<(MROWS * (D_INNER / 4) + 255) / 256, blk, 0, stream>>>(
            xz_ws, conv_W + (size_t)i * D_INNER * D_CONV, conv_b + i * D_INNER, u_ws);

        // x_dbl = u @ x_proj_W[i].T  (MFMA, N=56 guarded, split-K=6, atomic)
        hipMemsetAsync(xdbl_ws, 0, (size_t)MROWS * XPROJ_N * sizeof(float), stream);
        mfma_gemm<0, false, true, false, true><<<dim3(1, MROWS / 64, 6), blk, 0, stream>>>(
            u_ws, x_proj_W + (size_t)i * XPROJ_N * D_INNER, nullptr, nullptr, nullptr,
            xdbl_ws, MROWS, XPROJ_N, D_INNER, D_INNER, 0, XPROJ_N, 128);

        // delta = softplus(x_dbl[:, :24] @ dt_proj_W[i].T + dt_proj_b[i])  (f32)
        gemm_bt<2><<<dim3(D_INNER / BN, MROWS / BM, 1), blk, 0, stream>>>(
            xdbl_ws, dt_proj_W + (size_t)i * D_INNER * DT_RANK,
            dt_proj_b + i * D_INNER,
            delta_ws, MROWS, D_INNER, DT_RANK, XPROJ_N, D_INNER);

        // chunked selective scan (pass 1: local, pass 2: prefix fix)
        scan1_k<<<dim3(D_INNER / 16, NCH, B_), blk, 0, stream>>>(
            delta_ws, u_ws, xdbl_ws, A_log + (size_t)i * D_INNER * N_STATE,
            Dp + i * D_INNER, y_ws, P_ws, H_ws);
        scan2_k<<<dim3(D_INNER / 16, NCH - 1, B_), blk, 0, stream>>>(
            delta_ws, xdbl_ws, A_log + (size_t)i * D_INNER * N_STATE,
            P_ws, H_ws, y_ws);

        // x += (y * silu(res)) @ out_proj_W.T  (MFMA, gated A, split-K=2, atomic)
        mfma_gemm<0, true, true, false, false><<<dim3(D_MODEL / 64, MROWS / 64, 2), blk, 0, stream>>>(
            y_ws, out_proj_W + (size_t)i * D_MODEL * D_INNER, nullptr, xz_ws + D_INNER,
            nullptr, x_ws, MROWS, D_MODEL, D_INNER, D_INNER, 2 * D_INNER, D_MODEL, 384);
    }

    // out = rmsnorm(x, normf_W) @ head_W.T  (MFMA, rmsnorm fused)
    mfma_gemm<0, false, false, true, false><<<dim3(FEAT / 64, MROWS / 64, 1), blk, 0, stream>>>(
        x_ws, head_W, nullptr, nullptr, normf_W, out,
        MROWS, FEAT, D_MODEL, D_MODEL, 0, FEAT, D_MODEL);
}

// Round 9
// 727.843 us; speedup vs baseline: 2.2325x; 1.0441x over previous
//
#include <hip/hip_runtime.h>
#include <math.h>

// Problem dims
#define B_ 4
#define L_ 512
#define MROWS 2048
#define D_MODEL 384
#define N_LAYER 4
#define D_INNER 768
#define N_STATE 16
#define DT_RANK 24
#define D_CONV 4
#define VOCAB 1544
#define FEAT 1536
#define XPROJ_N 56
#define NCH 8               // scan chunks per batch (L/64)
#define SCH 64              // scan chunk length

typedef __attribute__((ext_vector_type(8))) short short8;
typedef __attribute__((ext_vector_type(4))) float floatx4;

__device__ __forceinline__ float softplus_f(float x) { return x > 20.f ? x : log1pf(expf(x)); }
__device__ __forceinline__ float silu_f(float x) { return x / (1.f + __expf(-x)); }

// f32 -> bf16 (RNE), two packed into one u32
__device__ __forceinline__ unsigned pack2bf(float x, float y) {
    unsigned ux = __float_as_uint(x); ux = (ux + 0x7FFFu + ((ux >> 16) & 1u)) >> 16;
    unsigned uy = __float_as_uint(y); uy = (uy + 0x7FFFu + ((uy >> 16) & 1u)) >> 16;
    return ux | (uy << 16);
}

// DPP row-rotate add: x + (x rotated by N within each 16-lane row).
template <int CTRL>
__device__ __forceinline__ float dpp_radd(float x) {
    int r = __builtin_amdgcn_update_dpp(0, __float_as_int(x), CTRL, 0xf, 0xf, true);
    return x + __int_as_float(r);
}

__device__ __forceinline__ float4 ld4_guard(const float* __restrict__ p, int k, int ke) {
    if (k + 3 < ke) return *(const float4*)(p + k);
    float4 r = make_float4(0.f, 0.f, 0.f, 0.f);
    if (k + 0 < ke) r.x = p[k + 0];
    if (k + 1 < ke) r.y = p[k + 1];
    if (k + 2 < ke) r.z = p[k + 2];
    return r;
}

__device__ __forceinline__ short8 ld8h_guard(const short* __restrict__ p, int k, int ke) {
    if (k + 7 < ke) return *(const short8*)(p + k);
    short8 r = {0, 0, 0, 0, 0, 0, 0, 0};
#pragma unroll
    for (int j = 0; j < 8; ++j)
        if (k + j < ke) r[j] = p[k + j];
    return r;
}

// ---------------------------------------------------------------------------
// One-shot weight cast f32 -> bf16 (weights constant per launch; casting them
// per-tile in the GEMMs was half the staging VALU cost — r8 MfmaUtil 1.9%).
// ---------------------------------------------------------------------------
struct CastDesc {
    const float* src[6];
    short*       dst[6];
    unsigned     cum[6];   // exclusive prefix ends, in float4 units
};

__global__ __launch_bounds__(256) void cast_w_k(CastDesc cd, unsigned total4)
{
    unsigned i = blockIdx.x * 256 + threadIdx.x;
    if (i >= total4) return;
    int s = 0;
#pragma unroll
    for (int j = 0; j < 5; ++j)
        if (i >= cd.cum[j] && s == j) s = j + 1;
    unsigned off = i - (s ? cd.cum[s - 1] : 0u);
    float4 v = ((const float4*)cd.src[s])[off];
    uint2 pk;
    pk.x = pack2bf(v.x, v.y);
    pk.y = pack2bf(v.z, v.w);
    ((uint2*)cd.dst[s])[off] = pk;
}

// ---------------------------------------------------------------------------
// MFMA bf16 GEMM: C[m,n] (+)= sum_k A[m,k]*W[n,k].
// W is PRE-CAST bf16 (row-major NxK): staging = one guarded 16B copy.
// ABF: A also pre-cast bf16 (copy staging). Else A f32 with pack (+GATED/RMSN).
// 64x64 tile, 4 waves, 2x2 v_mfma_f32_16x16x32_bf16 each; K-step 32, dbuf.
// EPI: 0 none, 1 +bias (z==0 if ATOMIC), 2 softplus(v+bias) (non-atomic).
// NG: guard W rows / C cols >= N.
// ---------------------------------------------------------------------------
#define ASTR 40

template <int EPI, bool GATED, bool ATOMIC, bool RMSN, bool NG, bool ABF>
__global__ __launch_bounds__(256) void mfma_gemm(
    const float* __restrict__ A, const short* __restrict__ Abf,
    const short* __restrict__ Wb,
    const float* __restrict__ bias, const float* __restrict__ gate,
    const float* __restrict__ nw,
    float* __restrict__ C, int M, int N, int K, int lda, int ldg, int ldc, int KC)
{
    __shared__ short As[2][64 * ASTR];
    __shared__ short Ws[2][64 * ASTR];
    __shared__ float sscale[64];

    const int t  = threadIdx.x;
    const int m0 = blockIdx.y * 64;
    const int n0 = blockIdx.x * 64;
    const int ks = blockIdx.z * KC;
    const int ke = min(K, ks + KC);

    const int srow = t >> 2;           // 0..63
    const int sseg = (t & 3) * 8;      // 0,8,16,24

    if (RMSN) {
        const int row = t >> 2, q = t & 3;
        const float* xr = A + (size_t)(m0 + row) * lda + q * (K >> 2);
        float s = 0.f;
        for (int i = 0; i < (K >> 2); i += 4) {
            float4 v = *(const float4*)(xr + i);
            s += v.x * v.x + v.y * v.y + v.z * v.z + v.w * v.w;
        }
        s += __shfl_xor(s, 1, 64);
        s += __shfl_xor(s, 2, 64);
        if (q == 0) sscale[row] = rsqrtf(s / (float)K + 1e-5f);
        __syncthreads();
    }

    float4 ra0, ra1, rg0, rg1, rn0, rn1;
    short8 ra8, rw8;

    auto prefetch = [&](int k0) {
        if (ABF) {
            ra8 = ld8h_guard(Abf + (size_t)(m0 + srow) * lda, k0 + sseg, ke);
        } else {
            const float* ar = A + (size_t)(m0 + srow) * lda;
            ra0 = ld4_guard(ar, k0 + sseg, ke);
            ra1 = ld4_guard(ar, k0 + sseg + 4, ke);
            if (GATED) {
                const float* gr = gate + (size_t)(m0 + srow) * ldg;
                rg0 = ld4_guard(gr, k0 + sseg, ke);
                rg1 = ld4_guard(gr, k0 + sseg + 4, ke);
            }
            if (RMSN) {
                rn0 = ld4_guard(nw, k0 + sseg, ke);
                rn1 = ld4_guard(nw, k0 + sseg + 4, ke);
            }
        }
        if (!NG || (n0 + srow) < N) {
            rw8 = ld8h_guard(Wb + (size_t)(n0 + srow) * (size_t)K, k0 + sseg, ke);
        } else {
            rw8 = (short8){0, 0, 0, 0, 0, 0, 0, 0};
        }
    };

    auto stage = [&](int p) {
        if (ABF) {
            *(short8*)&As[p][srow * ASTR + sseg] = ra8;
        } else {
            float4 a0 = ra0, a1 = ra1;
            if (GATED) {
                a0.x *= silu_f(rg0.x); a0.y *= silu_f(rg0.y); a0.z *= silu_f(rg0.z); a0.w *= silu_f(rg0.w);
                a1.x *= silu_f(rg1.x); a1.y *= silu_f(rg1.y); a1.z *= silu_f(rg1.z); a1.w *= silu_f(rg1.w);
            }
            if (RMSN) {
                float sc = sscale[srow];
                a0.x *= sc * rn0.x; a0.y *= sc * rn0.y; a0.z *= sc * rn0.z; a0.w *= sc * rn0.w;
                a1.x *= sc * rn1.x; a1.y *= sc * rn1.y; a1.z *= sc * rn1.z; a1.w *= sc * rn1.w;
            }
            int4 pa;
            pa.x = pack2bf(a0.x, a0.y); pa.y = pack2bf(a0.z, a0.w);
            pa.z = pack2bf(a1.x, a1.y); pa.w = pack2bf(a1.z, a1.w);
            *(int4*)&As[p][srow * ASTR + sseg] = pa;
        }
        *(short8*)&Ws[p][srow * ASTR + sseg] = rw8;
    };

    prefetch(ks);
    stage(0);
    __syncthreads();

    floatx4 acc[2][2];
#pragma unroll
    for (int i = 0; i < 2; ++i)
#pragma unroll
        for (int j = 0; j < 2; ++j) acc[i][j] = (floatx4){0.f, 0.f, 0.f, 0.f};

    const int w    = t >> 6;
    const int lane = t & 63;
    const int quad = lane >> 4;
    const int lm   = lane & 15;
    const int aoff = ((w >> 1) * 32 + lm) * ASTR + quad * 8;
    const int boff = ((w & 1) * 32 + lm) * ASTR + quad * 8;

    int p = 0;
    for (int k0 = ks; k0 < ke; k0 += 32) {
        const bool more = (k0 + 32 < ke);
        if (more) prefetch(k0 + 32);
        short8 a0 = *(const short8*)&As[p][aoff];
        short8 a1 = *(const short8*)&As[p][aoff + 16 * ASTR];
        short8 b0 = *(const short8*)&Ws[p][boff];
        short8 b1 = *(const short8*)&Ws[p][boff + 16 * ASTR];
        acc[0][0] = __builtin_amdgcn_mfma_f32_16x16x32_bf16(a0, b0, acc[0][0], 0, 0, 0);
        acc[0][1] = __builtin_amdgcn_mfma_f32_16x16x32_bf16(a0, b1, acc[0][1], 0, 0, 0);
        acc[1][0] = __builtin_amdgcn_mfma_f32_16x16x32_bf16(a1, b0, acc[1][0], 0, 0, 0);
        acc[1][1] = __builtin_amdgcn_mfma_f32_16x16x32_bf16(a1, b1, acc[1][1], 0, 0, 0);
        if (more) {
            stage(p ^ 1);
            __syncthreads();
            p ^= 1;
        }
    }

    const int rbase = m0 + (w >> 1) * 32 + quad * 4;
    const int cbase = n0 + (w & 1) * 32 + lm;
#pragma unroll
    for (int mt = 0; mt < 2; ++mt)
#pragma unroll
        for (int nt = 0; nt < 2; ++nt) {
            const int gc = cbase + nt * 16;
            if (NG && gc >= N) continue;
#pragma unroll
            for (int r = 0; r < 4; ++r) {
                const size_t gr = rbase + mt * 16 + r;
                float v = acc[mt][nt][r];
                if (ATOMIC) {
                    if (EPI == 1 && blockIdx.z == 0) v += bias[gc];
                    atomicAdd(&C[gr * ldc + gc], v);
                } else {
                    if (EPI == 1) v += bias[gc];
                    if (EPI == 2) v = softplus_f(v + bias[gc]);
                    C[gr * ldc + gc] = v;
                }
            }
        }
}

// ---------------------------------------------------------------------------
// Depthwise causal conv (width 4) + bias + SiLU; writes u (f32) and u_bf.
// ---------------------------------------------------------------------------
__global__ __launch_bounds__(256) void conv_silu_k(
    const float* __restrict__ xz, const float* __restrict__ w,
    const float* __restrict__ cb, float* __restrict__ u, short* __restrict__ ubf)
{
    int idx = blockIdx.x * 256 + threadIdx.x;
    if (idx >= MROWS * (D_INNER / 4)) return;
    int dq = idx % (D_INNER / 4);
    int m  = idx / (D_INNER / 4);
    int d0 = dq * 4;
    int b = m / L_, l = m % L_;
    float4 wq[4];
#pragma unroll
    for (int j = 0; j < 4; ++j) wq[j] = *(const float4*)(w + (d0 + j) * D_CONV);
    float acc[4];
#pragma unroll
    for (int j = 0; j < 4; ++j) acc[j] = cb[d0 + j];
#pragma unroll
    for (int tt = 0; tt < 4; ++tt) {
        int ll = l - 3 + tt;
        if (ll >= 0) {
            float4 xv = *(const float4*)(xz + (size_t)(b * L_ + ll) * (2 * D_INNER) + d0);
            acc[0] = fmaf(xv.x, ((const float*)&wq[0])[tt], acc[0]);
            acc[1] = fmaf(xv.y, ((const float*)&wq[1])[tt], acc[1]);
            acc[2] = fmaf(xv.z, ((const float*)&wq[2])[tt], acc[2]);
            acc[3] = fmaf(xv.w, ((const float*)&wq[3])[tt], acc[3]);
        }
    }
    float4 o = make_float4(silu_f(acc[0]), silu_f(acc[1]), silu_f(acc[2]), silu_f(acc[3]));
    *(float4*)(u + (size_t)m * D_INNER + d0) = o;
    uint2 pk;
    pk.x = pack2bf(o.x, o.y);
    pk.y = pack2bf(o.z, o.w);
    *(uint2*)(ubf + (size_t)m * D_INNER + d0) = pk;
}

// ---------------------------------------------------------------------------
// Chunked selective scan, pass 1 (local, h0=0): y_local, P=prod(e), H=end h.
// grid (48, NCH, B_), block = 16 d x 16 n.
// ---------------------------------------------------------------------------
__global__ __launch_bounds__(256) void scan1_k(
    const float* __restrict__ delta, const float* __restrict__ u,
    const float* __restrict__ xdbl, const float* __restrict__ A_log,
    const float* __restrict__ Dp, float* __restrict__ y,
    float* __restrict__ Pws, float* __restrict__ Hws)
{
    __shared__ float sd[SCH][16], su[SCH][16], sB[SCH][16], sC[SCH][16];
    const int t  = threadIdx.x;
    const int n  = t & 15;
    const int dl = t >> 4;
    const int dg = blockIdx.x;
    const int c  = blockIdx.y;
    const int b  = blockIdx.z;
    const int d  = dg * 16 + dl;
    const int l0 = c * SCH;

    const float Av = -expf(A_log[d * N_STATE + n]);
    const float Dd = Dp[d];
    const int lr = t >> 2;
    const int lc = (t & 3) << 2;

    {
        const size_t mrow = (size_t)b * L_ + l0 + lr;
        *(float4*)&sd[lr][lc] = *(const float4*)(delta + mrow * D_INNER + dg * 16 + lc);
        *(float4*)&su[lr][lc] = *(const float4*)(u     + mrow * D_INNER + dg * 16 + lc);
        *(float4*)&sB[lr][lc] = *(const float4*)(xdbl  + mrow * XPROJ_N + DT_RANK + lc);
        *(float4*)&sC[lr][lc] = *(const float4*)(xdbl  + mrow * XPROJ_N + DT_RANK + N_STATE + lc);
    }
    __syncthreads();

    float h = 0.f, pacc = 1.f;
#pragma unroll 8
    for (int j = 0; j < SCH; ++j) {
        float dv = sd[j][dl];
        float uv = su[j][dl];
        float e  = __expf(dv * Av);
        float cc = dv * uv * sB[j][n];
        h = fmaf(e, h, cc);
        pacc *= e;
        float p = h * sC[j][n];
        p = dpp_radd<0x128>(p);
        p = dpp_radd<0x124>(p);
        p = dpp_radd<0x122>(p);
        p = dpp_radd<0x121>(p);
        if (n == 0) y[((size_t)b * L_ + l0 + j) * D_INNER + d] = fmaf(uv, Dd, p);
    }
    const size_t phi = (((size_t)(b * NCH + c) * D_INNER + dg * 16 + dl) << 4) + n;
    Pws[phi] = pacc;
    Hws[phi] = h;
}

// ---------------------------------------------------------------------------
// Chunked selective scan, pass 2: add carry-in contribution for chunks 1..7.
// ---------------------------------------------------------------------------
__global__ __launch_bounds__(256) void scan2_k(
    const float* __restrict__ delta, const float* __restrict__ xdbl,
    const float* __restrict__ A_log,
    const float* __restrict__ Pws, const float* __restrict__ Hws,
    float* __restrict__ y)
{
    __shared__ float sd[SCH][16], sC[SCH][16];
    const int t  = threadIdx.x;
    const int n  = t & 15;
    const int dl = t >> 4;
    const int dg = blockIdx.x;
    const int c  = blockIdx.y + 1;
    const int b  = blockIdx.z;
    const int d  = dg * 16 + dl;
    const int l0 = c * SCH;

    const float Av = -expf(A_log[d * N_STATE + n]);

    float hs = 0.f;
    for (int s = 0; s < c; ++s) {
        const size_t phi = (((size_t)(b * NCH + s) * D_INNER + d) << 4) + n;
        hs = fmaf(Pws[phi], hs, Hws[phi]);
    }

    const int lr = t >> 2;
    const int lc = (t & 3) << 2;
    {
        const size_t mrow = (size_t)b * L_ + l0 + lr;
        *(float4*)&sd[lr][lc] = *(const float4*)(delta + mrow * D_INNER + dg * 16 + lc);
        *(float4*)&sC[lr][lc] = *(const float4*)(xdbl  + mrow * XPROJ_N + DT_RANK + N_STATE + lc);
    }
    __syncthreads();

    float g = hs;
#pragma unroll 8
    for (int j = 0; j < SCH; ++j) {
        float dv = sd[j][dl];
        g *= __expf(dv * Av);
        float p = g * sC[j][n];
        p = dpp_radd<0x128>(p);
        p = dpp_radd<0x124>(p);
        p = dpp_radd<0x122>(p);
        p = dpp_radd<0x121>(p);
        if (n == 0) y[((size_t)b * L_ + l0 + j) * D_INNER + d] += p;
    }
}

// ---------------------------------------------------------------------------
extern "C" void kernel_launch(void* const* d_in, const int* in_sizes, int n_in,
                              void* d_out, int out_size, void* d_ws, size_t ws_size,
                              hipStream_t stream)
{
    const float* input_ids = (const float*)d_in[0];
    const float* fc_W      = (const float*)d_in[1];
    const float* fc_b      = (const float*)d_in[2];
    const float* in_proj_W = (const float*)d_in[3];
    const float* conv_W    = (const float*)d_in[4];
    const float* conv_b    = (const float*)d_in[5];
    const float* x_proj_W  = (const float*)d_in[6];
    const float* dt_proj_W = (const float*)d_in[7];
    const float* dt_proj_b = (const float*)d_in[8];
    const float* A_log     = (const float*)d_in[9];
    const float* Dp        = (const float*)d_in[10];
    const float* out_proj_W= (const float*)d_in[11];
    const float* norm_W    = (const float*)d_in[12];
    const float* normf_W   = (const float*)d_in[13];
    const float* head_W    = (const float*)d_in[14];
    float* out = (float*)d_out;

    float* ws       = (float*)d_ws;
    float* x_ws     = ws;                                    // M*384
    float* xz_ws    = x_ws    + (size_t)MROWS * D_MODEL;     // M*1536
    float* u_ws     = xz_ws   + (size_t)MROWS * 2 * D_INNER; // M*768
    float* xdbl_ws  = u_ws    + (size_t)MROWS * D_INNER;     // M*56
    float* delta_ws = xdbl_ws + (size_t)MROWS * XPROJ_N;     // M*768
    float* y_ws     = delta_ws+ (size_t)MROWS * D_INNER;     // M*768
    float* P_ws     = y_ws    + (size_t)MROWS * D_INNER;     // B*8*768*16
    float* H_ws     = P_ws    + (size_t)B_ * NCH * D_INNER * N_STATE;
    // bf16 region (16B-aligned: all prior sizes are multiples of 4 floats)
    short* bf       = (short*)(H_ws + (size_t)B_ * NCH * D_INNER * N_STATE);
    short* wbf_fc   = bf;                                          // 384*1544
    short* wbf_in   = wbf_fc  + (size_t)D_MODEL * VOCAB;           // 4*1536*384
    short* wbf_x    = wbf_in  + (size_t)N_LAYER * 2 * D_INNER * D_MODEL; // 4*56*768
    short* wbf_dt   = wbf_x   + (size_t)N_LAYER * XPROJ_N * D_INNER;     // 4*768*24
    short* wbf_out  = wbf_dt  + (size_t)N_LAYER * D_INNER * DT_RANK;     // 4*384*768
    short* wbf_head = wbf_out + (size_t)N_LAYER * D_MODEL * D_INNER;     // 1536*384
    short* ubf_ws   = wbf_head+ (size_t)FEAT * D_MODEL;            // M*768

    const dim3 blk(256);

    // --- one-shot weight cast to bf16 ---
    CastDesc cd;
    cd.src[0] = fc_W;       cd.dst[0] = wbf_fc;
    cd.src[1] = in_proj_W;  cd.dst[1] = wbf_in;
    cd.src[2] = x_proj_W;   cd.dst[2] = wbf_x;
    cd.src[3] = dt_proj_W;  cd.dst[3] = wbf_dt;
    cd.src[4] = out_proj_W; cd.dst[4] = wbf_out;
    cd.src[5] = head_W;     cd.dst[5] = wbf_head;
    unsigned c0 = (unsigned)(D_MODEL * VOCAB / 4);
    unsigned c1 = c0 + (unsigned)(N_LAYER * 2 * D_INNER * D_MODEL / 4);
    unsigned c2 = c1 + (unsigned)(N_LAYER * XPROJ_N * D_INNER / 4);
    unsigned c3 = c2 + (unsigned)(N_LAYER * D_INNER * DT_RANK / 4);
    unsigned c4 = c3 + (unsigned)(N_LAYER * D_MODEL * D_INNER / 4);
    unsigned c5 = c4 + (unsigned)(FEAT * D_MODEL / 4);
    cd.cum[0] = c0; cd.cum[1] = c1; cd.cum[2] = c2;
    cd.cum[3] = c3; cd.cum[4] = c4; cd.cum[5] = c5;
    cast_w_k<<<(c5 + 255) / 256, blk, 0, stream>>>(cd, c5);

    // x = input_ids @ fc_W.T + fc_b   (split-K=6 -> 1152 blocks, atomic)
    hipMemsetAsync(x_ws, 0, (size_t)MROWS * D_MODEL * sizeof(float), stream);
    mfma_gemm<1, false, true, false, false, false><<<dim3(D_MODEL / 64, MROWS / 64, 6), blk, 0, stream>>>(
        input_ids, nullptr, wbf_fc, fc_b, nullptr, nullptr, x_ws,
        MROWS, D_MODEL, VOCAB, VOCAB, 0, D_MODEL, 264);

    for (int i = 0; i < N_LAYER; ++i) {
        // xz = rmsnorm(x, norm_W) @ in_proj_W.T   (rmsnorm fused into A staging)
        mfma_gemm<0, false, false, true, false, false><<<dim3(2 * D_INNER / 64, MROWS / 64, 1), blk, 0, stream>>>(
            x_ws, nullptr, wbf_in + (size_t)i * 2 * D_INNER * D_MODEL,
            nullptr, nullptr, norm_W + i * D_MODEL, xz_ws,
            MROWS, 2 * D_INNER, D_MODEL, D_MODEL, 0, 2 * D_INNER, D_MODEL);

        // u = silu(conv(xz[:, :768]) + conv_b)  (f32 + bf16 copies)
        conv_silu_k<<<(MROWS * (D_INNER / 4) + 255) / 256, blk, 0, stream>>>(
            xz_ws, conv_W + (size_t)i * D_INNER * D_CONV, conv_b + i * D_INNER,
            u_ws, ubf_ws);

        // x_dbl = u @ x_proj_W[i].T  (A pre-cast bf16, N=56 guarded, split-K=6)
        hipMemsetAsync(xdbl_ws, 0, (size_t)MROWS * XPROJ_N * sizeof(float), stream);
        mfma_gemm<0, false, true, false, true, true><<<dim3(1, MROWS / 64, 6), blk, 0, stream>>>(
            nullptr, ubf_ws, wbf_x + (size_t)i * XPROJ_N * D_INNER,
            nullptr, nullptr, nullptr, xdbl_ws,
            MROWS, XPROJ_N, D_INNER, D_INNER, 0, XPROJ_N, 128);

        // delta = softplus(x_dbl[:, :24] @ dt_proj_W[i].T + dt_proj_b[i])  (MFMA, 1 k-iter)
        mfma_gemm<2, false, false, false, false, false><<<dim3(D_INNER / 64, MROWS / 64, 1), blk, 0, stream>>>(
            xdbl_ws, nullptr, wbf_dt + (size_t)i * D_INNER * DT_RANK,
            dt_proj_b + i * D_INNER, nullptr, nullptr, delta_ws,
            MROWS, D_INNER, DT_RANK, XPROJ_N, 0, D_INNER, DT_RANK);

        // chunked selective scan (pass 1: local, pass 2: prefix fix)
        scan1_k<<<dim3(D_INNER / 16, NCH, B_), blk, 0, stream>>>(
            delta_ws, u_ws, xdbl_ws, A_log + (size_t)i * D_INNER * N_STATE,
            Dp + i * D_INNER, y_ws, P_ws, H_ws);
        scan2_k<<<dim3(D_INNER / 16, NCH - 1, B_), blk, 0, stream>>>(
            delta_ws, xdbl_ws, A_log + (size_t)i * D_INNER * N_STATE,
            P_ws, H_ws, y_ws);

        // x += (y * silu(res)) @ out_proj_W.T  (gated A, split-K=2, atomic residual)
        mfma_gemm<0, true, true, false, false, false><<<dim3(D_MODEL / 64, MROWS / 64, 2), blk, 0, stream>>>(
            y_ws, nullptr, wbf_out + (size_t)i * D_MODEL * D_INNER,
            nullptr, xz_ws + D_INNER, nullptr, x_ws,
            MROWS, D_MODEL, D_INNER, D_INNER, 2 * D_INNER, D_MODEL, 384);
    }

    // out = rmsnorm(x, normf_W) @ head_W.T  (rmsnorm fused)
    mfma_gemm<0, false, false, true, false, false><<<dim3(FEAT / 64, MROWS / 64, 1), blk, 0, stream>>>(
        x_ws, nullptr, wbf_head, nullptr, nullptr, normf_W, out,
        MROWS, FEAT, D_MODEL, D_MODEL, 0, FEAT, D_MODEL);
}

// Round 10
// 679.632 us; speedup vs baseline: 2.3909x; 1.0709x over previous
//
#include <hip/hip_runtime.h>
#include <math.h>

// Problem dims
#define B_ 4
#define L_ 512
#define MROWS 2048
#define D_MODEL 384
#define N_LAYER 4
#define D_INNER 768
#define N_STATE 16
#define DT_RANK 24
#define D_CONV 4
#define VOCAB 1544
#define FEAT 1536
#define XPROJ_N 56
#define NCH 8               // scan chunks per batch (L/64)
#define SCH 64              // scan chunk length

typedef __attribute__((ext_vector_type(8))) short short8;
typedef __attribute__((ext_vector_type(4))) float floatx4;

__device__ __forceinline__ float softplus_f(float x) { return x > 20.f ? x : log1pf(expf(x)); }
__device__ __forceinline__ float silu_f(float x) { return x / (1.f + __expf(-x)); }

// f32 -> bf16 (RNE), two packed into one u32
__device__ __forceinline__ unsigned pack2bf(float x, float y) {
    unsigned ux = __float_as_uint(x); ux = (ux + 0x7FFFu + ((ux >> 16) & 1u)) >> 16;
    unsigned uy = __float_as_uint(y); uy = (uy + 0x7FFFu + ((uy >> 16) & 1u)) >> 16;
    return ux | (uy << 16);
}

// DPP row-rotate add: x + (x rotated by N within each 16-lane row).
template <int CTRL>
__device__ __forceinline__ float dpp_radd(float x) {
    int r = __builtin_amdgcn_update_dpp(0, __float_as_int(x), CTRL, 0xf, 0xf, true);
    return x + __int_as_float(r);
}

__device__ __forceinline__ float4 ld4_guard(const float* __restrict__ p, int k, int ke) {
    if (k + 3 < ke) return *(const float4*)(p + k);
    float4 r = make_float4(0.f, 0.f, 0.f, 0.f);
    if (k + 0 < ke) r.x = p[k + 0];
    if (k + 1 < ke) r.y = p[k + 1];
    if (k + 2 < ke) r.z = p[k + 2];
    return r;
}

__device__ __forceinline__ short8 ld8h_guard(const short* __restrict__ p, int k, int ke) {
    if (k + 7 < ke) return *(const short8*)(p + k);
    short8 r = {0, 0, 0, 0, 0, 0, 0, 0};
#pragma unroll
    for (int j = 0; j < 8; ++j)
        if (k + j < ke) r[j] = p[k + j];
    return r;
}

// ---------------------------------------------------------------------------
// One-shot weight cast f32 -> bf16.
// ---------------------------------------------------------------------------
struct CastDesc {
    const float* src[6];
    short*       dst[6];
    unsigned     cum[6];   // exclusive prefix ends, in float4 units
};

__global__ __launch_bounds__(256) void cast_w_k(CastDesc cd, unsigned total4)
{
    unsigned i = blockIdx.x * 256 + threadIdx.x;
    if (i >= total4) return;
    int s = 0;
#pragma unroll
    for (int j = 0; j < 5; ++j)
        if (i >= cd.cum[j] && s == j) s = j + 1;
    unsigned off = i - (s ? cd.cum[s - 1] : 0u);
    float4 v = ((const float4*)cd.src[s])[off];
    uint2 pk;
    pk.x = pack2bf(v.x, v.y);
    pk.y = pack2bf(v.z, v.w);
    ((uint2*)cd.dst[s])[off] = pk;
}

// ---------------------------------------------------------------------------
// MFMA bf16 GEMM: C[m,n] (+)= sum_k A[m,k]*W[n,k].  W pre-cast bf16.
// Pipelined K-loop: stage(k+1) -> prefetch(k+2) -> MFMA(k) -> barrier, so
// global loads get a FULL iteration of latency cover (r9: MfmaUtil 2%, the
// old stage-after-MFMA order gave loads only ~100cy before the vmcnt drain).
// ABF: A pre-cast bf16. EPI: 0 none, 1 +bias(z==0 if ATOMIC), 2 softplus+bias.
// ---------------------------------------------------------------------------
#define ASTR 40

template <int EPI, bool GATED, bool ATOMIC, bool RMSN, bool NG, bool ABF>
__global__ __launch_bounds__(256) void mfma_gemm(
    const float* __restrict__ A, const short* __restrict__ Abf,
    const short* __restrict__ Wb,
    const float* __restrict__ bias, const float* __restrict__ gate,
    const float* __restrict__ nw,
    float* __restrict__ C, int M, int N, int K, int lda, int ldg, int ldc, int KC)
{
    __shared__ short As[2][64 * ASTR];
    __shared__ short Ws[2][64 * ASTR];
    __shared__ float sscale[64];

    const int t  = threadIdx.x;
    const int m0 = blockIdx.y * 64;
    const int n0 = blockIdx.x * 64;
    const int ks = blockIdx.z * KC;
    const int ke = min(K, ks + KC);

    const int srow = t >> 2;           // 0..63
    const int sseg = (t & 3) * 8;      // 0,8,16,24

    if (RMSN) {
        const int row = t >> 2, q = t & 3;
        const float* xr = A + (size_t)(m0 + row) * lda + q * (K >> 2);
        float s = 0.f;
        for (int i = 0; i < (K >> 2); i += 4) {
            float4 v = *(const float4*)(xr + i);
            s += v.x * v.x + v.y * v.y + v.z * v.z + v.w * v.w;
        }
        s += __shfl_xor(s, 1, 64);
        s += __shfl_xor(s, 2, 64);
        if (q == 0) sscale[row] = rsqrtf(s / (float)K + 1e-5f);
        __syncthreads();
    }

    float4 ra0, ra1, rg0, rg1, rn0, rn1;
    short8 ra8, rw8;

    auto prefetch = [&](int k0) {
        if (ABF) {
            ra8 = ld8h_guard(Abf + (size_t)(m0 + srow) * lda, k0 + sseg, ke);
        } else {
            const float* ar = A + (size_t)(m0 + srow) * lda;
            ra0 = ld4_guard(ar, k0 + sseg, ke);
            ra1 = ld4_guard(ar, k0 + sseg + 4, ke);
            if (GATED) {
                const float* gr = gate + (size_t)(m0 + srow) * ldg;
                rg0 = ld4_guard(gr, k0 + sseg, ke);
                rg1 = ld4_guard(gr, k0 + sseg + 4, ke);
            }
            if (RMSN) {
                rn0 = ld4_guard(nw, k0 + sseg, ke);
                rn1 = ld4_guard(nw, k0 + sseg + 4, ke);
            }
        }
        if (!NG || (n0 + srow) < N) {
            rw8 = ld8h_guard(Wb + (size_t)(n0 + srow) * (size_t)K, k0 + sseg, ke);
        } else {
            rw8 = (short8){0, 0, 0, 0, 0, 0, 0, 0};
        }
    };

    auto stage = [&](int p) {
        if (ABF) {
            *(short8*)&As[p][srow * ASTR + sseg] = ra8;
        } else {
            float4 a0 = ra0, a1 = ra1;
            if (GATED) {
                a0.x *= silu_f(rg0.x); a0.y *= silu_f(rg0.y); a0.z *= silu_f(rg0.z); a0.w *= silu_f(rg0.w);
                a1.x *= silu_f(rg1.x); a1.y *= silu_f(rg1.y); a1.z *= silu_f(rg1.z); a1.w *= silu_f(rg1.w);
            }
            if (RMSN) {
                float sc = sscale[srow];
                a0.x *= sc * rn0.x; a0.y *= sc * rn0.y; a0.z *= sc * rn0.z; a0.w *= sc * rn0.w;
                a1.x *= sc * rn1.x; a1.y *= sc * rn1.y; a1.z *= sc * rn1.z; a1.w *= sc * rn1.w;
            }
            int4 pa;
            pa.x = pack2bf(a0.x, a0.y); pa.y = pack2bf(a0.z, a0.w);
            pa.z = pack2bf(a1.x, a1.y); pa.w = pack2bf(a1.z, a1.w);
            *(int4*)&As[p][srow * ASTR + sseg] = pa;
        }
        *(short8*)&Ws[p][srow * ASTR + sseg] = rw8;
    };

    prefetch(ks);
    stage(0);
    if (ks + 32 < ke) prefetch(ks + 32);   // loads for iter 2 in flight across barrier
    __syncthreads();

    floatx4 acc[2][2];
#pragma unroll
    for (int i = 0; i < 2; ++i)
#pragma unroll
        for (int j = 0; j < 2; ++j) acc[i][j] = (floatx4){0.f, 0.f, 0.f, 0.f};

    const int w    = t >> 6;
    const int lane = t & 63;
    const int quad = lane >> 4;
    const int lm   = lane & 15;
    const int aoff = ((w >> 1) * 32 + lm) * ASTR + quad * 8;
    const int boff = ((w & 1) * 32 + lm) * ASTR + quad * 8;

    int p = 0;
    for (int k0 = ks; k0 < ke; k0 += 32) {
        const bool more = (k0 + 32 < ke);
        if (more) {
            stage(p ^ 1);                       // consumes loads issued 1 iter ago
            if (k0 + 64 < ke) prefetch(k0 + 64); // issue 2 iters ahead
        }
        short8 a0 = *(const short8*)&As[p][aoff];
        short8 a1 = *(const short8*)&As[p][aoff + 16 * ASTR];
        short8 b0 = *(const short8*)&Ws[p][boff];
        short8 b1 = *(const short8*)&Ws[p][boff + 16 * ASTR];
        acc[0][0] = __builtin_amdgcn_mfma_f32_16x16x32_bf16(a0, b0, acc[0][0], 0, 0, 0);
        acc[0][1] = __builtin_amdgcn_mfma_f32_16x16x32_bf16(a0, b1, acc[0][1], 0, 0, 0);
        acc[1][0] = __builtin_amdgcn_mfma_f32_16x16x32_bf16(a1, b0, acc[1][0], 0, 0, 0);
        acc[1][1] = __builtin_amdgcn_mfma_f32_16x16x32_bf16(a1, b1, acc[1][1], 0, 0, 0);
        if (more) {
            __syncthreads();
            p ^= 1;
        }
    }

    const int rbase = m0 + (w >> 1) * 32 + quad * 4;
    const int cbase = n0 + (w & 1) * 32 + lm;
#pragma unroll
    for (int mt = 0; mt < 2; ++mt)
#pragma unroll
        for (int nt = 0; nt < 2; ++nt) {
            const int gc = cbase + nt * 16;
            if (NG && gc >= N) continue;
#pragma unroll
            for (int r = 0; r < 4; ++r) {
                const size_t gr = rbase + mt * 16 + r;
                float v = acc[mt][nt][r];
                if (ATOMIC) {
                    if (EPI == 1 && blockIdx.z == 0) v += bias[gc];
                    atomicAdd(&C[gr * ldc + gc], v);
                } else {
                    if (EPI == 1) v += bias[gc];
                    if (EPI == 2) v = softplus_f(v + bias[gc]);
                    C[gr * ldc + gc] = v;
                }
            }
        }
}

// ---------------------------------------------------------------------------
// Depthwise causal conv (width 4) + bias + SiLU; writes u (f32) and u_bf.
// ---------------------------------------------------------------------------
__global__ __launch_bounds__(256) void conv_silu_k(
    const float* __restrict__ xz, const float* __restrict__ w,
    const float* __restrict__ cb, float* __restrict__ u, short* __restrict__ ubf)
{
    int idx = blockIdx.x * 256 + threadIdx.x;
    if (idx >= MROWS * (D_INNER / 4)) return;
    int dq = idx % (D_INNER / 4);
    int m  = idx / (D_INNER / 4);
    int d0 = dq * 4;
    int b = m / L_, l = m % L_;
    float4 wq[4];
#pragma unroll
    for (int j = 0; j < 4; ++j) wq[j] = *(const float4*)(w + (d0 + j) * D_CONV);
    float acc[4];
#pragma unroll
    for (int j = 0; j < 4; ++j) acc[j] = cb[d0 + j];
#pragma unroll
    for (int tt = 0; tt < 4; ++tt) {
        int ll = l - 3 + tt;
        if (ll >= 0) {
            float4 xv = *(const float4*)(xz + (size_t)(b * L_ + ll) * (2 * D_INNER) + d0);
            acc[0] = fmaf(xv.x, ((const float*)&wq[0])[tt], acc[0]);
            acc[1] = fmaf(xv.y, ((const float*)&wq[1])[tt], acc[1]);
            acc[2] = fmaf(xv.z, ((const float*)&wq[2])[tt], acc[2]);
            acc[3] = fmaf(xv.w, ((const float*)&wq[3])[tt], acc[3]);
        }
    }
    float4 o = make_float4(silu_f(acc[0]), silu_f(acc[1]), silu_f(acc[2]), silu_f(acc[3]));
    *(float4*)(u + (size_t)m * D_INNER + d0) = o;
    uint2 pk;
    pk.x = pack2bf(o.x, o.y);
    pk.y = pack2bf(o.z, o.w);
    *(uint2*)(ubf + (size_t)m * D_INNER + d0) = pk;
}

// ---------------------------------------------------------------------------
// Chunked selective scan, pass 1 (local, h0=0): y_local, P=prod(e), H=end h.
// ---------------------------------------------------------------------------
__global__ __launch_bounds__(256) void scan1_k(
    const float* __restrict__ delta, const float* __restrict__ u,
    const float* __restrict__ xdbl, const float* __restrict__ A_log,
    const float* __restrict__ Dp, float* __restrict__ y,
    float* __restrict__ Pws, float* __restrict__ Hws)
{
    __shared__ float sd[SCH][16], su[SCH][16], sB[SCH][16], sC[SCH][16];
    const int t  = threadIdx.x;
    const int n  = t & 15;
    const int dl = t >> 4;
    const int dg = blockIdx.x;
    const int c  = blockIdx.y;
    const int b  = blockIdx.z;
    const int d  = dg * 16 + dl;
    const int l0 = c * SCH;

    const float Av = -expf(A_log[d * N_STATE + n]);
    const float Dd = Dp[d];
    const int lr = t >> 2;
    const int lc = (t & 3) << 2;

    {
        const size_t mrow = (size_t)b * L_ + l0 + lr;
        *(float4*)&sd[lr][lc] = *(const float4*)(delta + mrow * D_INNER + dg * 16 + lc);
        *(float4*)&su[lr][lc] = *(const float4*)(u     + mrow * D_INNER + dg * 16 + lc);
        *(float4*)&sB[lr][lc] = *(const float4*)(xdbl  + mrow * XPROJ_N + DT_RANK + lc);
        *(float4*)&sC[lr][lc] = *(const float4*)(xdbl  + mrow * XPROJ_N + DT_RANK + N_STATE + lc);
    }
    __syncthreads();

    float h = 0.f, pacc = 1.f;
#pragma unroll 8
    for (int j = 0; j < SCH; ++j) {
        float dv = sd[j][dl];
        float uv = su[j][dl];
        float e  = __expf(dv * Av);
        float cc = dv * uv * sB[j][n];
        h = fmaf(e, h, cc);
        pacc *= e;
        float p = h * sC[j][n];
        p = dpp_radd<0x128>(p);
        p = dpp_radd<0x124>(p);
        p = dpp_radd<0x122>(p);
        p = dpp_radd<0x121>(p);
        if (n == 0) y[((size_t)b * L_ + l0 + j) * D_INNER + d] = fmaf(uv, Dd, p);
    }
    const size_t phi = (((size_t)(b * NCH + c) * D_INNER + dg * 16 + dl) << 4) + n;
    Pws[phi] = pacc;
    Hws[phi] = h;
}

// ---------------------------------------------------------------------------
// Chunked selective scan, pass 2: add carry-in contribution for chunks 1..7.
// ---------------------------------------------------------------------------
__global__ __launch_bounds__(256) void scan2_k(
    const float* __restrict__ delta, const float* __restrict__ xdbl,
    const float* __restrict__ A_log,
    const float* __restrict__ Pws, const float* __restrict__ Hws,
    float* __restrict__ y)
{
    __shared__ float sd[SCH][16], sC[SCH][16];
    const int t  = threadIdx.x;
    const int n  = t & 15;
    const int dl = t >> 4;
    const int dg = blockIdx.x;
    const int c  = blockIdx.y + 1;
    const int b  = blockIdx.z;
    const int d  = dg * 16 + dl;
    const int l0 = c * SCH;

    const float Av = -expf(A_log[d * N_STATE + n]);

    float hs = 0.f;
    for (int s = 0; s < c; ++s) {
        const size_t phi = (((size_t)(b * NCH + s) * D_INNER + d) << 4) + n;
        hs = fmaf(Pws[phi], hs, Hws[phi]);
    }

    const int lr = t >> 2;
    const int lc = (t & 3) << 2;
    {
        const size_t mrow = (size_t)b * L_ + l0 + lr;
        *(float4*)&sd[lr][lc] = *(const float4*)(delta + mrow * D_INNER + dg * 16 + lc);
        *(float4*)&sC[lr][lc] = *(const float4*)(xdbl  + mrow * XPROJ_N + DT_RANK + N_STATE + lc);
    }
    __syncthreads();

    float g = hs;
#pragma unroll 8
    for (int j = 0; j < SCH; ++j) {
        float dv = sd[j][dl];
        g *= __expf(dv * Av);
        float p = g * sC[j][n];
        p = dpp_radd<0x128>(p);
        p = dpp_radd<0x124>(p);
        p = dpp_radd<0x122>(p);
        p = dpp_radd<0x121>(p);
        if (n == 0) y[((size_t)b * L_ + l0 + j) * D_INNER + d] += p;
    }
}

// ---------------------------------------------------------------------------
extern "C" void kernel_launch(void* const* d_in, const int* in_sizes, int n_in,
                              void* d_out, int out_size, void* d_ws, size_t ws_size,
                              hipStream_t stream)
{
    const float* input_ids = (const float*)d_in[0];
    const float* fc_W      = (const float*)d_in[1];
    const float* fc_b      = (const float*)d_in[2];
    const float* in_proj_W = (const float*)d_in[3];
    const float* conv_W    = (const float*)d_in[4];
    const float* conv_b    = (const float*)d_in[5];
    const float* x_proj_W  = (const float*)d_in[6];
    const float* dt_proj_W = (const float*)d_in[7];
    const float* dt_proj_b = (const float*)d_in[8];
    const float* A_log     = (const float*)d_in[9];
    const float* Dp        = (const float*)d_in[10];
    const float* out_proj_W= (const float*)d_in[11];
    const float* norm_W    = (const float*)d_in[12];
    const float* normf_W   = (const float*)d_in[13];
    const float* head_W    = (const float*)d_in[14];
    float* out = (float*)d_out;

    float* ws       = (float*)d_ws;
    float* x_ws     = ws;                                    // M*384
    float* xz_ws    = x_ws    + (size_t)MROWS * D_MODEL;     // M*1536
    float* u_ws     = xz_ws   + (size_t)MROWS * 2 * D_INNER; // M*768
    float* xdbl_ws  = u_ws    + (size_t)MROWS * D_INNER;     // M*56
    float* delta_ws = xdbl_ws + (size_t)MROWS * XPROJ_N;     // M*768
    float* y_ws     = delta_ws+ (size_t)MROWS * D_INNER;     // M*768
    float* P_ws     = y_ws    + (size_t)MROWS * D_INNER;     // B*8*768*16
    float* H_ws     = P_ws    + (size_t)B_ * NCH * D_INNER * N_STATE;
    short* bf       = (short*)(H_ws + (size_t)B_ * NCH * D_INNER * N_STATE);
    short* wbf_fc   = bf;
    short* wbf_in   = wbf_fc  + (size_t)D_MODEL * VOCAB;
    short* wbf_x    = wbf_in  + (size_t)N_LAYER * 2 * D_INNER * D_MODEL;
    short* wbf_dt   = wbf_x   + (size_t)N_LAYER * XPROJ_N * D_INNER;
    short* wbf_out  = wbf_dt  + (size_t)N_LAYER * D_INNER * DT_RANK;
    short* wbf_head = wbf_out + (size_t)N_LAYER * D_MODEL * D_INNER;
    short* ubf_ws   = wbf_head+ (size_t)FEAT * D_MODEL;

    const dim3 blk(256);

    // --- one-shot weight cast to bf16 ---
    CastDesc cd;
    cd.src[0] = fc_W;       cd.dst[0] = wbf_fc;
    cd.src[1] = in_proj_W;  cd.dst[1] = wbf_in;
    cd.src[2] = x_proj_W;   cd.dst[2] = wbf_x;
    cd.src[3] = dt_proj_W;  cd.dst[3] = wbf_dt;
    cd.src[4] = out_proj_W; cd.dst[4] = wbf_out;
    cd.src[5] = head_W;     cd.dst[5] = wbf_head;
    unsigned c0 = (unsigned)(D_MODEL * VOCAB / 4);
    unsigned c1 = c0 + (unsigned)(N_LAYER * 2 * D_INNER * D_MODEL / 4);
    unsigned c2 = c1 + (unsigned)(N_LAYER * XPROJ_N * D_INNER / 4);
    unsigned c3 = c2 + (unsigned)(N_LAYER * D_INNER * DT_RANK / 4);
    unsigned c4 = c3 + (unsigned)(N_LAYER * D_MODEL * D_INNER / 4);
    unsigned c5 = c4 + (unsigned)(FEAT * D_MODEL / 4);
    cd.cum[0] = c0; cd.cum[1] = c1; cd.cum[2] = c2;
    cd.cum[3] = c3; cd.cum[4] = c4; cd.cum[5] = c5;
    cast_w_k<<<(c5 + 255) / 256, blk, 0, stream>>>(cd, c5);

    // x = input_ids @ fc_W.T + fc_b   (split-K=7, KC=256 aligned to K-step)
    hipMemsetAsync(x_ws, 0, (size_t)MROWS * D_MODEL * sizeof(float), stream);
    mfma_gemm<1, false, true, false, false, false><<<dim3(D_MODEL / 64, MROWS / 64, 7), blk, 0, stream>>>(
        input_ids, nullptr, wbf_fc, fc_b, nullptr, nullptr, x_ws,
        MROWS, D_MODEL, VOCAB, VOCAB, 0, D_MODEL, 256);

    for (int i = 0; i < N_LAYER; ++i) {
        // xz = rmsnorm(x, norm_W) @ in_proj_W.T   (rmsnorm fused into A staging)
        mfma_gemm<0, false, false, true, false, false><<<dim3(2 * D_INNER / 64, MROWS / 64, 1), blk, 0, stream>>>(
            x_ws, nullptr, wbf_in + (size_t)i * 2 * D_INNER * D_MODEL,
            nullptr, nullptr, norm_W + i * D_MODEL, xz_ws,
            MROWS, 2 * D_INNER, D_MODEL, D_MODEL, 0, 2 * D_INNER, D_MODEL);

        // u = silu(conv(xz[:, :768]) + conv_b)  (f32 + bf16 copies)
        conv_silu_k<<<(MROWS * (D_INNER / 4) + 255) / 256, blk, 0, stream>>>(
            xz_ws, conv_W + (size_t)i * D_INNER * D_CONV, conv_b + i * D_INNER,
            u_ws, ubf_ws);

        // x_dbl = u @ x_proj_W[i].T  (A pre-cast bf16, N=56 guarded, split-K=6)
        hipMemsetAsync(xdbl_ws, 0, (size_t)MROWS * XPROJ_N * sizeof(float), stream);
        mfma_gemm<0, false, true, false, true, true><<<dim3(1, MROWS / 64, 6), blk, 0, stream>>>(
            nullptr, ubf_ws, wbf_x + (size_t)i * XPROJ_N * D_INNER,
            nullptr, nullptr, nullptr, xdbl_ws,
            MROWS, XPROJ_N, D_INNER, D_INNER, 0, XPROJ_N, 128);

        // delta = softplus(x_dbl[:, :24] @ dt_proj_W[i].T + dt_proj_b[i])  (1 k-iter)
        mfma_gemm<2, false, false, false, false, false><<<dim3(D_INNER / 64, MROWS / 64, 1), blk, 0, stream>>>(
            xdbl_ws, nullptr, wbf_dt + (size_t)i * D_INNER * DT_RANK,
            dt_proj_b + i * D_INNER, nullptr, nullptr, delta_ws,
            MROWS, D_INNER, DT_RANK, XPROJ_N, 0, D_INNER, DT_RANK);

        // chunked selective scan (pass 1: local, pass 2: prefix fix)
        scan1_k<<<dim3(D_INNER / 16, NCH, B_), blk, 0, stream>>>(
            delta_ws, u_ws, xdbl_ws, A_log + (size_t)i * D_INNER * N_STATE,
            Dp + i * D_INNER, y_ws, P_ws, H_ws);
        scan2_k<<<dim3(D_INNER / 16, NCH - 1, B_), blk, 0, stream>>>(
            delta_ws, xdbl_ws, A_log + (size_t)i * D_INNER * N_STATE,
            P_ws, H_ws, y_ws);

        // x += (y * silu(res)) @ out_proj_W.T  (gated A, split-K=2, atomic residual)
        mfma_gemm<0, true, true, false, false, false><<<dim3(D_MODEL / 64, MROWS / 64, 2), blk, 0, stream>>>(
            y_ws, nullptr, wbf_out + (size_t)i * D_MODEL * D_INNER,
            nullptr, xz_ws + D_INNER, nullptr, x_ws,
            MROWS, D_MODEL, D_INNER, D_INNER, 2 * D_INNER, D_MODEL, 384);
    }

    // out = rmsnorm(x, normf_W) @ head_W.T  (rmsnorm fused)
    mfma_gemm<0, false, false, true, false, false><<<dim3(FEAT / 64, MROWS / 64, 1), blk, 0, stream>>>(
        x_ws, nullptr, wbf_head, nullptr, nullptr, normf_W, out,
        MROWS, FEAT, D_MODEL, D_MODEL, 0, FEAT, D_MODEL);
}